// Round 11
// baseline (339.553 us; speedup 1.0000x reference)
//
#include <hip/hip_runtime.h>
#include <math.h>

// ---------- types / helpers ----------
typedef short s8x __attribute__((ext_vector_type(8)));    // 8 bf16 (4 VGPRs) MFMA A/B frag
typedef float f32x4 __attribute__((ext_vector_type(4)));  // 16x16 MFMA C/D frag
typedef int   i32x2 __attribute__((ext_vector_type(2)));  // 64-bit tr-read result

__device__ __forceinline__ float bf2f(short u) {
    return __uint_as_float(((unsigned int)(unsigned short)u) << 16);
}
__device__ __forceinline__ short f2bf(float f) {
    unsigned int x = __float_as_uint(f);
    unsigned int r = (x + 0x7FFFu + ((x >> 16) & 1u)) >> 16; // RNE
    return (short)(unsigned short)r;
}

// async global->LDS, 16B per lane. LDS dest must be wave-uniform base + lane*16.
__device__ __forceinline__ void gl2lds16(const short* g, const short* l) {
    __builtin_amdgcn_global_load_lds(
        (const __attribute__((address_space(1))) void*)(unsigned long long)g,
        (__attribute__((address_space(3))) void*)(unsigned int)(unsigned long long)l,
        16, 0, 0);
}

// raw barrier with compiler memory fences (no vmcnt(0) drain, unlike __syncthreads)
__device__ __forceinline__ void block_sync() {
    asm volatile("" ::: "memory");
    __builtin_amdgcn_s_barrier();
    asm volatile("" ::: "memory");
}
#define WAITV(n) asm volatile("s_waitcnt vmcnt(" #n ")" ::: "memory")

// ---------- wave-per-row LayerNorm core: f32 in -> bf16 out, C=1024 ----------
__device__ __forceinline__ void ln_row(const float* __restrict__ xin,
                                       const float* __restrict__ w,
                                       const float* __restrict__ bb,
                                       short* __restrict__ out, int row, int lane) {
    const float4* xr = (const float4*)(xin + (long)row * 1024);
    float4 v[4];
    float s1 = 0.f, s2 = 0.f;
#pragma unroll
    for (int i = 0; i < 4; ++i) {
        v[i] = xr[lane + i * 64];
        s1 += v[i].x + v[i].y + v[i].z + v[i].w;
        s2 += v[i].x*v[i].x + v[i].y*v[i].y + v[i].z*v[i].z + v[i].w*v[i].w;
    }
#pragma unroll
    for (int off = 32; off > 0; off >>= 1) {
        s1 += __shfl_xor(s1, off, 64);
        s2 += __shfl_xor(s2, off, 64);
    }
    const float mu = s1 * (1.0f / 1024.0f);
    float var = s2 * (1.0f / 1024.0f) - mu * mu;
    var = fmaxf(var, 0.0f);
    const float rs = rsqrtf(var + 1e-5f);
    short4* orow = (short4*)(out + (long)row * 1024);
#pragma unroll
    for (int i = 0; i < 4; ++i) {
        const int ci = (lane + i * 64) * 4;
        const float4 wv = *(const float4*)(w + ci);
        const float4 bv = *(const float4*)(bb + ci);
        short4 o;
        o.x = f2bf((v[i].x - mu) * rs * wv.x + bv.x);
        o.y = f2bf((v[i].y - mu) * rs * wv.y + bv.y);
        o.z = f2bf((v[i].z - mu) * rs * wv.z + bv.z);
        o.w = f2bf((v[i].w - mu) * rs * wv.w + bv.w);
        orow[lane + i * 64] = o;
    }
}

__global__ __launch_bounds__(256) void ln_k(const float* __restrict__ xin,
                                            const float* __restrict__ w,
                                            const float* __restrict__ bb,
                                            short* __restrict__ out) {
    ln_row(xin, w, bb, out, blockIdx.x * 4 + (threadIdx.x >> 6), threadIdx.x & 63);
}

// ---------- fused: 4 weight transposes (f32 [K][N] -> bf16 [N][K]) + LN1 ----------
__global__ __launch_bounds__(256) void pre_k(
        const float* __restrict__ w0, const float* __restrict__ w1,
        const float* __restrict__ w2, const float* __restrict__ w3,
        short* __restrict__ o0, short* __restrict__ o1,
        short* __restrict__ o2, short* __restrict__ o3,
        const float* __restrict__ x, const float* __restrict__ ln1w,
        const float* __restrict__ ln1b, short* __restrict__ xln) {
    int bid = blockIdx.x;
    if (bid >= 12288) {   // LN1: 1024 blocks, 4 rows each (wave per row)
        ln_row(x, ln1w, ln1b, xln, (bid - 12288) * 4 + (threadIdx.x >> 6), threadIdx.x & 63);
        return;
    }
    const float* in; short* out; int K, N, nx;
    if (bid < 3072)      { in = w0; out = o0; K = 1024; N = 3072; nx = 96; }
    else if (bid < 4096) { bid -= 3072; in = w1; out = o1; K = 1024; N = 1024; nx = 32; }
    else if (bid < 8192) { bid -= 4096; in = w2; out = o2; K = 1024; N = 4096; nx = 128; }
    else                 { bid -= 8192; in = w3; out = o3; K = 4096; N = 1024; nx = 32; }
    const int n0 = (bid % nx) * 32, k0 = (bid / nx) * 32;
    __shared__ float tile[32][33];
    const int tx = threadIdx.x & 31, ty = threadIdx.x >> 5; // ty 0..7
#pragma unroll
    for (int i = 0; i < 4; ++i) {
        const int k = ty + i * 8;
        tile[k][tx] = in[(long)(k0 + k) * N + n0 + tx];
    }
    __syncthreads();
#pragma unroll
    for (int i = 0; i < 4; ++i) {
        const int n = ty + i * 8;
        out[(long)(n0 + n) * K + k0 + tx] = f2bf(tile[tx][n]);
    }
}

// ---------- GEMM epilogue ----------
// EPI 1 GELU: tanh-form (sigmoid identity), |delta vs exact erf| < 3e-3 << bf16 tol.
// EPI 4: split-K partial — atomicAdd into f32 buffer that already holds the
//        residual (in-place accumulate; bias folded in by kz==0 at call site).
template <int EPI, typename OutT>
__device__ __forceinline__ void epi_store(OutT* out, const float* resid, long oidx, float v) {
    if constexpr (EPI == 0) {
        out[oidx] = f2bf(v);
    } else if constexpr (EPI == 1) {
        const float u = v * (0.79788456080f + 0.03567740814f * v * v);
        v = v / (1.0f + __expf(-2.0f * u));
        out[oidx] = f2bf(v);
    } else if constexpr (EPI == 4) {
        atomicAdd((float*)(out + oidx), v);
    } else {
        v += resid[oidx];
        out[oidx] = v;   // f32 store
    }
}

// ---------- GEMM 128x128, BK=32, TRIPLE-buffered, counted vmcnt, 1 barrier/step ----------
// LDS = 48 KB. Tile s+2 stages into buf (s+2)%3 == (s-1)%3, whose ds_reads all
// completed (they feed the pre-barrier MFMAs via compiler lgkmcnt waits) before
// any wave passed THIS barrier -> no WAR hazard, no second barrier. WAITV(4):
// tile s resident, tile s+1's 4 loads stay in flight across the barrier.
template <int EPI, typename OutT>
__global__ __launch_bounds__(256) void gemm_k(const short* __restrict__ A,
                                              const short* __restrict__ Bt,
                                              const float* __restrict__ bias,
                                              const float* __restrict__ resid,
                                              OutT* __restrict__ out,
                                              int M, int N, int K) {
    __shared__ __align__(16) short sA[3][128 * 32];
    __shared__ __align__(16) short sB[3][128 * 32];
    const int tid = threadIdx.x;
    const int lane = tid & 63, wave = tid >> 6;
    const int wr = (wave >> 1) * 64, wc = (wave & 1) * 64;
    const int lrow = lane & 15, quad = lane >> 4;
    const int bm = blockIdx.y * 128, bn = blockIdx.x * 128;
    const short* Ap = A + (long)(bm + (tid >> 2)) * K + (tid & 3) * 8;
    const short* Bp = Bt + (long)(bn + (tid >> 2)) * K + (tid & 3) * 8;
    const long rowstep = (long)64 * K;

    auto stage = [&](int q, int k0) {
        gl2lds16(Ap + k0,           sA[q] + tid * 8);
        gl2lds16(Ap + rowstep + k0, sA[q] + 2048 + tid * 8);
        gl2lds16(Bp + k0,           sB[q] + tid * 8);
        gl2lds16(Bp + rowstep + k0, sB[q] + 2048 + tid * 8);
    };

    f32x4 acc[4][4] = {};
    const int S = K >> 5;
    stage(0, 0);
    stage(1, 32);
    int cur = 0, nx2 = 2;
    for (int s = 0; s < S; ++s) {
        if (s + 1 < S) { WAITV(4); } else { WAITV(0); }   // tile s resident
        block_sync();
        if (s + 2 < S) stage(nx2, (s + 2) << 5);          // writes buf (s-1)%3: safe
        const short* pA = sA[cur];
        const short* pB = sB[cur];
        s8x af[4], bfr[4];
#pragma unroll
        for (int i = 0; i < 4; ++i) af[i]  = *(const s8x*)(pA + (wr + i*16 + lrow) * 32 + quad * 8);
#pragma unroll
        for (int j = 0; j < 4; ++j) bfr[j] = *(const s8x*)(pB + (wc + j*16 + lrow) * 32 + quad * 8);
#pragma unroll
        for (int i = 0; i < 4; ++i)
#pragma unroll
            for (int j = 0; j < 4; ++j)
                acc[i][j] = __builtin_amdgcn_mfma_f32_16x16x32_bf16(af[i], bfr[j], acc[i][j], 0, 0, 0);
        cur = (cur == 2) ? 0 : cur + 1;
        nx2 = (nx2 == 2) ? 0 : nx2 + 1;
    }
#pragma unroll
    for (int i = 0; i < 4; ++i) {
#pragma unroll
        for (int j = 0; j < 4; ++j) {
#pragma unroll
            for (int r = 0; r < 4; ++r) {
                const int row = bm + wr + i*16 + quad*4 + r;   // C/D: row = quad*4 + reg
                const int col = bn + wc + j*16 + lrow;         // C/D: col = lane&15
                epi_store<EPI>(out, resid, (long)row * N + col, acc[i][j][r] + bias[col]);
            }
        }
    }
}

// ---------- GEMM 128x64, BK=64 (2x32 panels), double-buffered, XCD-swizzled ----------
// Round-9-verified loop + optional split-K via blockIdx.z (each z-plane runs the
// identical loop over K/gridDim.z). Split-K raises resident blocks/CU 2->3 so
// one block's __syncthreads vmcnt drain hides under others' MFMAs (m114). With
// EPI=4 the output buffer already holds the residual; partials atomicAdd in
// (bias folded in by the kz==0 plane at the call site).
template <int EPI, typename OutT>
__global__ __launch_bounds__(256) void gemm128x64_k(const short* __restrict__ A,
                                                    const short* __restrict__ Bt,
                                                    const float* __restrict__ bias,
                                                    const float* __restrict__ resid,
                                                    OutT* __restrict__ out,
                                                    int M, int N, int K) {
    __shared__ __align__(16) short sA[2][2][128 * 32];
    __shared__ __align__(16) short sB[2][2][64 * 32];
    const int tid = threadIdx.x;
    const int lane = tid & 63, wave = tid >> 6;
    const int wr = (wave >> 1) * 64, wc = (wave & 1) * 32;
    const int lrow = lane & 15, quad = lane >> 4;
    // XCD-chunked bijective swizzle within the z-plane (nwg = 512, %8 == 0)
    const int gx = gridDim.x;
    const int nwg = gx * gridDim.y;
    const int bid = blockIdx.y * gx + blockIdx.x;
    const int swz = (bid & 7) * (nwg >> 3) + (bid >> 3);
    const int bm = (swz / gx) * 128, bn = (swz % gx) * 64;
    // split-K
    const int Kc = K / (int)gridDim.z;
    const int koff = (int)blockIdx.z * Kc;
    const float badd = (blockIdx.z == 0) ? 1.0f : 0.0f;
    const short* Ap = A + (long)(bm + (tid >> 2)) * K + koff + (tid & 3) * 8;
    const short* Bp = Bt + (long)(bn + (tid >> 2)) * K + koff + (tid & 3) * 8;
    const long rowstep = (long)64 * K;

    auto stage = [&](int p, int k0) {
#pragma unroll
        for (int hp = 0; hp < 2; ++hp) {
            gl2lds16(Ap + k0 + hp * 32,           sA[p][hp] + tid * 8);
            gl2lds16(Ap + rowstep + k0 + hp * 32, sA[p][hp] + 2048 + tid * 8);
            gl2lds16(Bp + k0 + hp * 32,           sB[p][hp] + tid * 8);
        }
    };

    f32x4 acc[4][2] = {};
    stage(0, 0);
    const int S = Kc >> 6;
    for (int s = 0; s < S; ++s) {
        const int p = s & 1;
        __syncthreads();
        if (s + 1 < S) stage(p ^ 1, (s + 1) << 6);
#pragma unroll
        for (int hp = 0; hp < 2; ++hp) {
            s8x af[4], bfr[2];
#pragma unroll
            for (int i = 0; i < 4; ++i) af[i]  = *(const s8x*)(sA[p][hp] + (wr + i*16 + lrow) * 32 + quad * 8);
#pragma unroll
            for (int j = 0; j < 2; ++j) bfr[j] = *(const s8x*)(sB[p][hp] + (wc + j*16 + lrow) * 32 + quad * 8);
#pragma unroll
            for (int i = 0; i < 4; ++i)
#pragma unroll
                for (int j = 0; j < 2; ++j)
                    acc[i][j] = __builtin_amdgcn_mfma_f32_16x16x32_bf16(af[i], bfr[j], acc[i][j], 0, 0, 0);
        }
    }
#pragma unroll
    for (int i = 0; i < 4; ++i) {
#pragma unroll
        for (int j = 0; j < 2; ++j) {
#pragma unroll
            for (int r = 0; r < 4; ++r) {
                const int row = bm + wr + i*16 + quad*4 + r;
                const int col = bn + wc + j*16 + lrow;
                epi_store<EPI>(out, resid, (long)row * N + col, acc[i][j][r] + bias[col] * badd);
            }
        }
    }
}

// ---------- attention common constants ----------
#define ATT_CS (0.125f * 1.4426950408889634f)  /* log2(e)/sqrt(64) */
#define ATT_C0 (14.426950408889634f)           /* 10*log2(e) fixed shift */

// hw transpose read: lane l receives column (l&15), rows j=0..3 of the [4][16]
// bf16 tile in the 128B window (l>>4); vaddr = base + lane*8B, offset literal.
#define TR16(dst, off) \
    asm volatile("ds_read_b64_tr_b16 %0, %1 offset:" off : "=v"(dst) : "v"(tva))

// ---------- paired-tile causal flash attention: B=2,H=16,T=2048,hs=64 ----------
// Pairs (bx, 31-bx): every block exactly 33 tile-iterations. Swapped QK^T
// (mfma(K,Q)) -> in-register softmax/l/pack + permlane rebuild of PV A-frag.
// V staged by direct global_load_lds DMA into tr_b16-compatible subtiled layout;
// PV B-frags via ds_read_b64_tr_b16 (shared by both q-tiles). Triple-buffered
// K/V (48 KB LDS) with counted vmcnt: next tile's loads fly across the barrier.
__global__ __launch_bounds__(256) void attn_k(const short* __restrict__ qkv,
                                              short* __restrict__ y) {
    const int bx = blockIdx.x;                 // 0..15
    const int b = blockIdx.y >> 4, h = blockIdx.y & 15;
    const int qtA = bx, qtB = 31 - bx;
    const int tid = threadIdx.x, lane = tid & 63, wave = tid >> 6;
    const int lrow = lane & 15, quad = lane >> 4;
    const long base = (long)b * 2048 * 3072;

    __shared__ __align__(16) short sK[3][64 * 64];
    __shared__ __align__(16) short sV[3][4096];

    s8x qfA0, qfA1, qfB0, qfB1;
    {
        const short* qpA = qkv + base + (long)(qtA * 64 + wave * 16 + lrow) * 3072 + h * 64 + quad * 8;
        qfA0 = *(const s8x*)qpA; qfA1 = *(const s8x*)(qpA + 32);
        const short* qpB = qkv + base + (long)(qtB * 64 + wave * 16 + lrow) * 3072 + h * 64 + quad * 8;
        qfB0 = *(const s8x*)qpB; qfB1 = *(const s8x*)(qpB + 32);
    }
    f32x4 oA[4], oB[4];
    float lA = 0.f, lB = 0.f;
#pragma unroll
    for (int d = 0; d < 4; ++d) { oA[d] = f32x4{0.f,0.f,0.f,0.f}; oB[d] = f32x4{0.f,0.f,0.f,0.f}; }

    // K staging (XOR-swizzled rows)
    const int srow = tid >> 3, sg = tid & 7;
    const int sw0 = ((srow & 7) ^ (srow >> 3)) & 7;
    const int sw1 = (((srow + 32) & 7) ^ ((srow + 32) >> 3)) & 7;
    const short* kbase = qkv + base + 1024 + h * 64;
    auto issueK = [&](int q, int k0) {
        gl2lds16(kbase + (long)(k0 + srow) * 3072      + (sg ^ sw0) * 8, sK[q] + tid * 8);
        gl2lds16(kbase + (long)(k0 + srow + 32) * 3072 + (sg ^ sw1) * 8, sK[q] + 2048 + tid * 8);
    };

    // V staging: pre-swizzled global source -> linear LDS (subtiled-for-tr layout)
    const int vslot   = (tid >> 3) & 7;
    const int vkbl    = 2 * (vslot & 3) + (vslot >> 2);
    const int vklocal = vkbl * 4 + ((tid >> 1) & 3);
    const short* vsrc = qkv + base + 2048 + h * 64
                      + (long)vklocal * 3072 + wave * 16 + 8 * (tid & 1);
    auto issueV = [&](int q, int k0) {
        gl2lds16(vsrc + (long)k0 * 3072,        sV[q] + tid * 8);        // ks=0 half
        gl2lds16(vsrc + (long)(k0 + 32) * 3072, sV[q] + 2048 + tid * 8); // ks=1 half
    };
    const unsigned trb = (unsigned)(unsigned long long)(&sV[0][0]) + (unsigned)lane * 8u;

    // swapped QK^T: st col = q (lane&15), row = key-local (quad*4+r)
    auto tile_step = [&](const s8x& qf0, const s8x& qf1, const s8x* kf0, const s8x* kf1,
                         const s8x (*vfr)[4], f32x4* o, float& lsum, int qt, int kt, int k0) {
        f32x4 s[4];
#pragma unroll
        for (int ct = 0; ct < 4; ++ct) {
            f32x4 t = f32x4{0.f, 0.f, 0.f, 0.f};
            t = __builtin_amdgcn_mfma_f32_16x16x32_bf16(kf0[ct], qf0, t, 0, 0, 0);
            t = __builtin_amdgcn_mfma_f32_16x16x32_bf16(kf1[ct], qf1, t, 0, 0, 0);
            s[ct] = t;
        }
        const int qrow = qt * 64 + wave * 16 + lrow;   // this lane's q
        float pv[4][4];
        if (kt == qt) {           // diagonal tile masking (uniform branch)
#pragma unroll
            for (int ct = 0; ct < 4; ++ct)
#pragma unroll
                for (int r = 0; r < 4; ++r) {
                    const int key = k0 + ct * 16 + quad * 4 + r;
                    const float pp = exp2f(fmaf(s[ct][r], ATT_CS, -ATT_C0));
                    const float pt = __uint_as_float(__float_as_uint(pp) & 0xFFFF0000u);
                    pv[ct][r] = (key > qrow) ? 0.f : pt;
                }
        } else {
#pragma unroll
            for (int ct = 0; ct < 4; ++ct)
#pragma unroll
                for (int r = 0; r < 4; ++r) {
                    const float pp = exp2f(fmaf(s[ct][r], ATT_CS, -ATT_C0));
                    pv[ct][r] = __uint_as_float(__float_as_uint(pp) & 0xFFFF0000u);
                }
        }
#pragma unroll
        for (int ct = 0; ct < 4; ++ct)
            lsum += (pv[ct][0] + pv[ct][1]) + (pv[ct][2] + pv[ct][3]);

        // pack P -> bf16 pairs: w2[ct][p] = keys {ct*16+4*quad+2p, +1} for q=lrow
        unsigned int w2[4][2];
#pragma unroll
        for (int ct = 0; ct < 4; ++ct)
#pragma unroll
            for (int p2 = 0; p2 < 2; ++p2)
                w2[ct][p2] = __builtin_amdgcn_perm(__float_as_uint(pv[ct][2 * p2 + 1]),
                                                   __float_as_uint(pv[ct][2 * p2]), 0x07060302u);
        // PV A-frag (lane needs P[q=lane&15][k=quad*8+e], e=0..7) via lane swaps
        s8x pa[2];
#pragma unroll
        for (int ks = 0; ks < 2; ++ks) {
            auto rAC = __builtin_amdgcn_permlane32_swap((int)w2[2 * ks][0], (int)w2[2 * ks + 1][0], false, false);
            auto rBD = __builtin_amdgcn_permlane32_swap((int)w2[2 * ks][1], (int)w2[2 * ks + 1][1], false, false);
            auto mAC = __builtin_amdgcn_permlane16_swap(rAC[0], rAC[1], false, false);
            auto mBD = __builtin_amdgcn_permlane16_swap(rBD[0], rBD[1], false, false);
            int4 f;
            f.x = mAC[0]; f.y = mBD[0]; f.z = mAC[1]; f.w = mBD[1];
            pa[ks] = *(const s8x*)&f;
        }
#pragma unroll
        for (int ks = 0; ks < 2; ++ks)
#pragma unroll
            for (int dt = 0; dt < 4; ++dt)
                o[dt] = __builtin_amdgcn_mfma_f32_16x16x32_bf16(pa[ks], vfr[ks][dt], o[dt], 0, 0, 0);
    };

    issueK(0, 0);   issueV(0, 0);
    issueK(1, 64);  issueV(1, 64);   // qtB >= 16: tile 1 always exists
    int cur = 0, nx2 = 2;
    for (int kt = 0; kt <= qtB; ++kt) {
        const int k0 = kt * 64;
        if (kt < qtB) { WAITV(4); } else { WAITV(0); }   // tile kt resident
        block_sync();
        if (kt + 2 <= qtB) { issueK(nx2, k0 + 128); issueV(nx2, k0 + 128); }

        // K fragments (compiler-managed LDS reads)
        s8x kf0[4], kf1[4];
#pragma unroll
        for (int ct = 0; ct < 4; ++ct) {
            const int row = ct * 16 + lrow;
            const int swr = ((row & 7) ^ (row >> 3)) & 7;
            kf0[ct] = *(const s8x*)(sK[cur] + row * 64 + ((quad ^ swr) * 8));
            kf1[ct] = *(const s8x*)(sK[cur] + row * 64 + (((4 + quad) ^ swr) * 8));
        }

        // V fragments via hw transpose reads (shared by both q-tiles)
        const unsigned tva = trb + (unsigned)(cur << 13);
        i32x2 tr[16];
        TR16(tr[0],  "0");    TR16(tr[1],  "512");
        TR16(tr[2],  "1024"); TR16(tr[3],  "1536");
        TR16(tr[4],  "2048"); TR16(tr[5],  "2560");
        TR16(tr[6],  "3072"); TR16(tr[7],  "3584");
        TR16(tr[8],  "4096"); TR16(tr[9],  "4608");
        TR16(tr[10], "5120"); TR16(tr[11], "5632");
        TR16(tr[12], "6144"); TR16(tr[13], "6656");
        TR16(tr[14], "7168"); TR16(tr[15], "7680");
        asm volatile("s_waitcnt lgkmcnt(0)" ::: "memory");
        __builtin_amdgcn_sched_barrier(0);       // rule #18: pin MFMAs after the wait
        s8x vfr[2][4];
#pragma unroll
        for (int ks = 0; ks < 2; ++ks)
#pragma unroll
            for (int dt = 0; dt < 4; ++dt) {
                const int i2 = ks * 8 + dt * 2;
                int4 f;
                f.x = tr[i2][0]; f.y = tr[i2][1];
                f.z = tr[i2 + 1][0]; f.w = tr[i2 + 1][1];
                vfr[ks][dt] = *(const s8x*)&f;
            }

        if (kt <= qtA) tile_step(qfA0, qfA1, kf0, kf1, vfr, oA, lA, qtA, kt, k0);
        tile_step(qfB0, qfB1, kf0, kf1, vfr, oB, lB, qtB, kt, k0);

        cur = (cur == 2) ? 0 : cur + 1;
        nx2 = (nx2 == 2) ? 0 : nx2 + 1;
    }

    // l lives per-lane at q=lane&15: reduce across quads, redistribute to C rows
    lA += __shfl_xor(lA, 16, 64); lA += __shfl_xor(lA, 32, 64);
    lB += __shfl_xor(lB, 16, 64); lB += __shfl_xor(lB, 32, 64);
    float rA[4], rB[4];
#pragma unroll
    for (int r = 0; r < 4; ++r) {
        rA[r] = 1.0f / __shfl(lA, quad * 4 + r, 64);
        rB[r] = 1.0f / __shfl(lB, quad * 4 + r, 64);
    }
#pragma unroll
    for (int dt = 0; dt < 4; ++dt) {
#pragma unroll
        for (int r = 0; r < 4; ++r) {
            const int qA = qtA * 64 + wave * 16 + quad * 4 + r;
            const int qB = qtB * 64 + wave * 16 + quad * 4 + r;
            y[((long)b * 2048 + qA) * 1024 + h * 64 + dt * 16 + lrow] = f2bf(oA[dt][r] * rA[r]);
            y[((long)b * 2048 + qB) * 1024 + h * 64 + dt * 16 + lrow] = f2bf(oB[dt][r] * rB[r]);
        }
    }
}

// ---------- launch ----------
extern "C" void kernel_launch(void* const* d_in, const int* in_sizes, int n_in,
                              void* d_out, int out_size, void* d_ws, size_t ws_size,
                              hipStream_t stream) {
    const float* x      = (const float*)d_in[0];
    const float* ln1_w  = (const float*)d_in[1];
    const float* ln1_b  = (const float*)d_in[2];
    const float* attn_w = (const float*)d_in[3];
    const float* attn_b = (const float*)d_in[4];
    const float* proj_w = (const float*)d_in[5];
    const float* proj_b = (const float*)d_in[6];
    const float* ln2_w  = (const float*)d_in[7];
    const float* ln2_b  = (const float*)d_in[8];
    const float* fc_w   = (const float*)d_in[9];
    const float* fc_b   = (const float*)d_in[10];
    const float* mlp_w  = (const float*)d_in[11];
    const float* mlp_b  = (const float*)d_in[12];

    char* ws = (char*)d_ws;
    short* attn_wt = (short*)(ws + 0);           // [3072,1024] bf16
    short* proj_wt = (short*)(ws + 6291456L);    // [1024,1024] bf16
    short* fc_wt   = (short*)(ws + 8388608L);    // [4096,1024] bf16
    short* mlp_wt  = (short*)(ws + 16777216L);   // [1024,4096] bf16
    short* slotA   = (short*)(ws + 25165824L);   // xln / y / h  [4096,1024] bf16
    short* slotB   = (short*)(ws + 33554432L);   // qkv [4096,3072] / hh [4096,4096] bf16
    // total ws use: 67,108,864 bytes (64 MB)

    short* xln  = slotA;
    short* yb   = slotA;
    short* hb   = slotA;
    short* qkvb = slotB;
    short* hh   = slotB;
    float* x1   = (float*)d_out;   // f32 residual stream lives in d_out
    float* outp = (float*)d_out;

    // transposes + LN1 fused (independent inputs)
    pre_k<<<13312, 256, 0, stream>>>(attn_w, proj_w, fc_w, mlp_w,
                                     attn_wt, proj_wt, fc_wt, mlp_wt,
                                     x, ln1_w, ln1_b, xln);

    gemm_k<0, short><<<dim3(24, 32), 256, 0, stream>>>(xln, attn_wt, attn_b, nullptr, qkvb, 4096, 3072, 1024);
    attn_k<<<dim3(16, 32), 256, 0, stream>>>(qkvb, yb);
    gemm128x64_k<2, float><<<dim3(16, 32), 256, 0, stream>>>(yb, proj_wt, proj_b, x, x1, 4096, 1024, 1024);
    ln_k<<<1024, 256, 0, stream>>>(x1, ln2_w, ln2_b, hb);
    gemm_k<1, short><<<dim3(32, 32), 256, 0, stream>>>(hb, fc_wt, fc_b, nullptr, hh, 4096, 4096, 1024);
    // mlp down-proj: split-K=2, partials atomicAdd into x1 (already = residual)
    gemm128x64_k<4, float><<<dim3(16, 32, 2), 256, 0, stream>>>(hh, mlp_wt, mlp_b, nullptr, outp, 4096, 1024, 4096);
}

// Round 12
// 329.981 us; speedup vs baseline: 1.0290x; 1.0290x over previous
//
#include <hip/hip_runtime.h>
#include <math.h>

// ---------- types / helpers ----------
typedef short s8x __attribute__((ext_vector_type(8)));    // 8 bf16 (4 VGPRs) MFMA A/B frag
typedef float f32x4 __attribute__((ext_vector_type(4)));  // 16x16 MFMA C/D frag
typedef int   i32x2 __attribute__((ext_vector_type(2)));  // 64-bit tr-read result

__device__ __forceinline__ float bf2f(short u) {
    return __uint_as_float(((unsigned int)(unsigned short)u) << 16);
}
__device__ __forceinline__ short f2bf(float f) {
    unsigned int x = __float_as_uint(f);
    unsigned int r = (x + 0x7FFFu + ((x >> 16) & 1u)) >> 16; // RNE
    return (short)(unsigned short)r;
}

// async global->LDS, 16B per lane. LDS dest must be wave-uniform base + lane*16.
__device__ __forceinline__ void gl2lds16(const short* g, const short* l) {
    __builtin_amdgcn_global_load_lds(
        (const __attribute__((address_space(1))) void*)(unsigned long long)g,
        (__attribute__((address_space(3))) void*)(unsigned int)(unsigned long long)l,
        16, 0, 0);
}

// raw barrier with compiler memory fences (no vmcnt(0) drain, unlike __syncthreads)
__device__ __forceinline__ void block_sync() {
    asm volatile("" ::: "memory");
    __builtin_amdgcn_s_barrier();
    asm volatile("" ::: "memory");
}
#define WAITV(n) asm volatile("s_waitcnt vmcnt(" #n ")" ::: "memory")

// ---------- wave-per-row LayerNorm core: f32 in -> bf16 out, C=1024 ----------
__device__ __forceinline__ void ln_row(const float* __restrict__ xin,
                                       const float* __restrict__ w,
                                       const float* __restrict__ bb,
                                       short* __restrict__ out, int row, int lane) {
    const float4* xr = (const float4*)(xin + (long)row * 1024);
    float4 v[4];
    float s1 = 0.f, s2 = 0.f;
#pragma unroll
    for (int i = 0; i < 4; ++i) {
        v[i] = xr[lane + i * 64];
        s1 += v[i].x + v[i].y + v[i].z + v[i].w;
        s2 += v[i].x*v[i].x + v[i].y*v[i].y + v[i].z*v[i].z + v[i].w*v[i].w;
    }
#pragma unroll
    for (int off = 32; off > 0; off >>= 1) {
        s1 += __shfl_xor(s1, off, 64);
        s2 += __shfl_xor(s2, off, 64);
    }
    const float mu = s1 * (1.0f / 1024.0f);
    float var = s2 * (1.0f / 1024.0f) - mu * mu;
    var = fmaxf(var, 0.0f);
    const float rs = rsqrtf(var + 1e-5f);
    short4* orow = (short4*)(out + (long)row * 1024);
#pragma unroll
    for (int i = 0; i < 4; ++i) {
        const int ci = (lane + i * 64) * 4;
        const float4 wv = *(const float4*)(w + ci);
        const float4 bv = *(const float4*)(bb + ci);
        short4 o;
        o.x = f2bf((v[i].x - mu) * rs * wv.x + bv.x);
        o.y = f2bf((v[i].y - mu) * rs * wv.y + bv.y);
        o.z = f2bf((v[i].z - mu) * rs * wv.z + bv.z);
        o.w = f2bf((v[i].w - mu) * rs * wv.w + bv.w);
        orow[lane + i * 64] = o;
    }
}

__global__ __launch_bounds__(256) void ln_k(const float* __restrict__ xin,
                                            const float* __restrict__ w,
                                            const float* __restrict__ bb,
                                            short* __restrict__ out) {
    ln_row(xin, w, bb, out, blockIdx.x * 4 + (threadIdx.x >> 6), threadIdx.x & 63);
}

// ---------- fused: 4 weight transposes (f32 [K][N] -> bf16 [N][K]) + LN1 ----------
__global__ __launch_bounds__(256) void pre_k(
        const float* __restrict__ w0, const float* __restrict__ w1,
        const float* __restrict__ w2, const float* __restrict__ w3,
        short* __restrict__ o0, short* __restrict__ o1,
        short* __restrict__ o2, short* __restrict__ o3,
        const float* __restrict__ x, const float* __restrict__ ln1w,
        const float* __restrict__ ln1b, short* __restrict__ xln) {
    int bid = blockIdx.x;
    if (bid >= 12288) {   // LN1: 1024 blocks, 4 rows each (wave per row)
        ln_row(x, ln1w, ln1b, xln, (bid - 12288) * 4 + (threadIdx.x >> 6), threadIdx.x & 63);
        return;
    }
    const float* in; short* out; int K, N, nx;
    if (bid < 3072)      { in = w0; out = o0; K = 1024; N = 3072; nx = 96; }
    else if (bid < 4096) { bid -= 3072; in = w1; out = o1; K = 1024; N = 1024; nx = 32; }
    else if (bid < 8192) { bid -= 4096; in = w2; out = o2; K = 1024; N = 4096; nx = 128; }
    else                 { bid -= 8192; in = w3; out = o3; K = 4096; N = 1024; nx = 32; }
    const int n0 = (bid % nx) * 32, k0 = (bid / nx) * 32;
    __shared__ float tile[32][33];
    const int tx = threadIdx.x & 31, ty = threadIdx.x >> 5; // ty 0..7
#pragma unroll
    for (int i = 0; i < 4; ++i) {
        const int k = ty + i * 8;
        tile[k][tx] = in[(long)(k0 + k) * N + n0 + tx];
    }
    __syncthreads();
#pragma unroll
    for (int i = 0; i < 4; ++i) {
        const int n = ty + i * 8;
        out[(long)(n0 + n) * K + k0 + tx] = f2bf(tile[tx][n]);
    }
}

// ---------- GEMM epilogue ----------
// EPI 1 GELU: tanh-form (sigmoid identity), |delta vs exact erf| < 3e-3 << bf16 tol.
template <int EPI, typename OutT>
__device__ __forceinline__ void epi_store(OutT* out, const float* resid, long oidx, float v) {
    if constexpr (EPI == 0) {
        out[oidx] = f2bf(v);
    } else if constexpr (EPI == 1) {
        const float u = v * (0.79788456080f + 0.03567740814f * v * v);
        v = v / (1.0f + __expf(-2.0f * u));
        out[oidx] = f2bf(v);
    } else {
        v += resid[oidx];
        out[oidx] = v;   // f32 store
    }
}

// ---------- GEMM 128x128, BK=32, TRIPLE-buffered, counted vmcnt, XCD-swizzled ----------
// LDS = 48 KB. Tile s+2 stages into buf (s+2)%3 == (s-1)%3, whose ds_reads all
// completed (they feed the pre-barrier MFMAs via compiler lgkmcnt waits) before
// any wave passed THIS barrier -> no WAR hazard, no second barrier. WAITV(4):
// tile s resident, tile s+1's 4 loads stay in flight across the barrier.
// XCD-chunked swizzle (proven -2.5x FETCH on gemm128x64): each XCD gets a
// contiguous chunk of the grid so A-panels become L2-local. nwg%8==0 required
// (fc: 1024, qkv: 768 — both OK).
template <int EPI, typename OutT>
__global__ __launch_bounds__(256) void gemm_k(const short* __restrict__ A,
                                              const short* __restrict__ Bt,
                                              const float* __restrict__ bias,
                                              const float* __restrict__ resid,
                                              OutT* __restrict__ out,
                                              int M, int N, int K) {
    __shared__ __align__(16) short sA[3][128 * 32];
    __shared__ __align__(16) short sB[3][128 * 32];
    const int tid = threadIdx.x;
    const int lane = tid & 63, wave = tid >> 6;
    const int wr = (wave >> 1) * 64, wc = (wave & 1) * 64;
    const int lrow = lane & 15, quad = lane >> 4;
    // XCD-chunked bijective swizzle
    const int gx = gridDim.x;
    const int nwg = gx * gridDim.y;
    const int bid = blockIdx.y * gx + blockIdx.x;
    const int swz = (bid & 7) * (nwg >> 3) + (bid >> 3);
    const int bm = (swz / gx) * 128, bn = (swz % gx) * 128;
    const short* Ap = A + (long)(bm + (tid >> 2)) * K + (tid & 3) * 8;
    const short* Bp = Bt + (long)(bn + (tid >> 2)) * K + (tid & 3) * 8;
    const long rowstep = (long)64 * K;

    auto stage = [&](int q, int k0) {
        gl2lds16(Ap + k0,           sA[q] + tid * 8);
        gl2lds16(Ap + rowstep + k0, sA[q] + 2048 + tid * 8);
        gl2lds16(Bp + k0,           sB[q] + tid * 8);
        gl2lds16(Bp + rowstep + k0, sB[q] + 2048 + tid * 8);
    };

    f32x4 acc[4][4] = {};
    const int S = K >> 5;
    stage(0, 0);
    stage(1, 32);
    int cur = 0, nx2 = 2;
    for (int s = 0; s < S; ++s) {
        if (s + 1 < S) { WAITV(4); } else { WAITV(0); }   // tile s resident
        block_sync();
        if (s + 2 < S) stage(nx2, (s + 2) << 5);          // writes buf (s-1)%3: safe
        const short* pA = sA[cur];
        const short* pB = sB[cur];
        s8x af[4], bfr[4];
#pragma unroll
        for (int i = 0; i < 4; ++i) af[i]  = *(const s8x*)(pA + (wr + i*16 + lrow) * 32 + quad * 8);
#pragma unroll
        for (int j = 0; j < 4; ++j) bfr[j] = *(const s8x*)(pB + (wc + j*16 + lrow) * 32 + quad * 8);
#pragma unroll
        for (int i = 0; i < 4; ++i)
#pragma unroll
            for (int j = 0; j < 4; ++j)
                acc[i][j] = __builtin_amdgcn_mfma_f32_16x16x32_bf16(af[i], bfr[j], acc[i][j], 0, 0, 0);
        cur = (cur == 2) ? 0 : cur + 1;
        nx2 = (nx2 == 2) ? 0 : nx2 + 1;
    }
#pragma unroll
    for (int i = 0; i < 4; ++i) {
#pragma unroll
        for (int j = 0; j < 4; ++j) {
#pragma unroll
            for (int r = 0; r < 4; ++r) {
                const int row = bm + wr + i*16 + quad*4 + r;   // C/D: row = quad*4 + reg
                const int col = bn + wc + j*16 + lrow;         // C/D: col = lane&15
                epi_store<EPI>(out, resid, (long)row * N + col, acc[i][j][r] + bias[col]);
            }
        }
    }
}

// ---------- GEMM 128x64, BK=64 (2x32 panels), double-buffered, XCD-swizzled ----------
// Round-9-verified best config for the skinny-N GEMMs (proj, mlp): 54.7 us mlp.
// Occupancy levers (BK=32 triple, 64x64 tile, split-K atomics) all measured
// WORSE — arithmetic-intensity damage exceeds latency-hiding gains here.
template <int EPI, typename OutT>
__global__ __launch_bounds__(256) void gemm128x64_k(const short* __restrict__ A,
                                                    const short* __restrict__ Bt,
                                                    const float* __restrict__ bias,
                                                    const float* __restrict__ resid,
                                                    OutT* __restrict__ out,
                                                    int M, int N, int K) {
    __shared__ __align__(16) short sA[2][2][128 * 32];
    __shared__ __align__(16) short sB[2][2][64 * 32];
    const int tid = threadIdx.x;
    const int lane = tid & 63, wave = tid >> 6;
    const int wr = (wave >> 1) * 64, wc = (wave & 1) * 32;
    const int lrow = lane & 15, quad = lane >> 4;
    // XCD-chunked bijective swizzle (nwg = 512, %8 == 0)
    const int gx = gridDim.x;
    const int nwg = gx * gridDim.y;
    const int bid = blockIdx.y * gx + blockIdx.x;
    const int swz = (bid & 7) * (nwg >> 3) + (bid >> 3);
    const int bm = (swz / gx) * 128, bn = (swz % gx) * 64;
    const short* Ap = A + (long)(bm + (tid >> 2)) * K + (tid & 3) * 8;
    const short* Bp = Bt + (long)(bn + (tid >> 2)) * K + (tid & 3) * 8;
    const long rowstep = (long)64 * K;

    auto stage = [&](int p, int k0) {
#pragma unroll
        for (int hp = 0; hp < 2; ++hp) {
            gl2lds16(Ap + k0 + hp * 32,           sA[p][hp] + tid * 8);
            gl2lds16(Ap + rowstep + k0 + hp * 32, sA[p][hp] + 2048 + tid * 8);
            gl2lds16(Bp + k0 + hp * 32,           sB[p][hp] + tid * 8);
        }
    };

    f32x4 acc[4][2] = {};
    stage(0, 0);
    const int S = K >> 6;
    for (int s = 0; s < S; ++s) {
        const int p = s & 1;
        __syncthreads();
        if (s + 1 < S) stage(p ^ 1, (s + 1) << 6);
#pragma unroll
        for (int hp = 0; hp < 2; ++hp) {
            s8x af[4], bfr[2];
#pragma unroll
            for (int i = 0; i < 4; ++i) af[i]  = *(const s8x*)(sA[p][hp] + (wr + i*16 + lrow) * 32 + quad * 8);
#pragma unroll
            for (int j = 0; j < 2; ++j) bfr[j] = *(const s8x*)(sB[p][hp] + (wc + j*16 + lrow) * 32 + quad * 8);
#pragma unroll
            for (int i = 0; i < 4; ++i)
#pragma unroll
                for (int j = 0; j < 2; ++j)
                    acc[i][j] = __builtin_amdgcn_mfma_f32_16x16x32_bf16(af[i], bfr[j], acc[i][j], 0, 0, 0);
        }
    }
#pragma unroll
    for (int i = 0; i < 4; ++i) {
#pragma unroll
        for (int j = 0; j < 2; ++j) {
#pragma unroll
            for (int r = 0; r < 4; ++r) {
                const int row = bm + wr + i*16 + quad*4 + r;
                const int col = bn + wc + j*16 + lrow;
                epi_store<EPI>(out, resid, (long)row * N + col, acc[i][j][r] + bias[col]);
            }
        }
    }
}

// ---------- attention common constants ----------
#define ATT_CS (0.125f * 1.4426950408889634f)  /* log2(e)/sqrt(64) */
#define ATT_C0 (14.426950408889634f)           /* 10*log2(e) fixed shift */

// hw transpose read: lane l receives column (l&15), rows j=0..3 of the [4][16]
// bf16 tile in the 128B window (l>>4); vaddr = base + lane*8B, offset literal.
#define TR16(dst, off) \
    asm volatile("ds_read_b64_tr_b16 %0, %1 offset:" off : "=v"(dst) : "v"(tva))

// ---------- paired-tile causal flash attention: B=2,H=16,T=2048,hs=64 ----------
// Pairs (bx, 31-bx): every block exactly 33 tile-iterations. Swapped QK^T
// (mfma(K,Q)) -> in-register softmax/l/pack + permlane rebuild of PV A-frag.
// V staged by direct global_load_lds DMA into tr_b16-compatible subtiled layout;
// PV B-frags via ds_read_b64_tr_b16 (shared by both q-tiles). Triple-buffered
// K/V (48 KB LDS) with counted vmcnt: next tile's loads fly across the barrier.
__global__ __launch_bounds__(256) void attn_k(const short* __restrict__ qkv,
                                              short* __restrict__ y) {
    const int bx = blockIdx.x;                 // 0..15
    const int b = blockIdx.y >> 4, h = blockIdx.y & 15;
    const int qtA = bx, qtB = 31 - bx;
    const int tid = threadIdx.x, lane = tid & 63, wave = tid >> 6;
    const int lrow = lane & 15, quad = lane >> 4;
    const long base = (long)b * 2048 * 3072;

    __shared__ __align__(16) short sK[3][64 * 64];
    __shared__ __align__(16) short sV[3][4096];

    s8x qfA0, qfA1, qfB0, qfB1;
    {
        const short* qpA = qkv + base + (long)(qtA * 64 + wave * 16 + lrow) * 3072 + h * 64 + quad * 8;
        qfA0 = *(const s8x*)qpA; qfA1 = *(const s8x*)(qpA + 32);
        const short* qpB = qkv + base + (long)(qtB * 64 + wave * 16 + lrow) * 3072 + h * 64 + quad * 8;
        qfB0 = *(const s8x*)qpB; qfB1 = *(const s8x*)(qpB + 32);
    }
    f32x4 oA[4], oB[4];
    float lA = 0.f, lB = 0.f;
#pragma unroll
    for (int d = 0; d < 4; ++d) { oA[d] = f32x4{0.f,0.f,0.f,0.f}; oB[d] = f32x4{0.f,0.f,0.f,0.f}; }

    // K staging (XOR-swizzled rows)
    const int srow = tid >> 3, sg = tid & 7;
    const int sw0 = ((srow & 7) ^ (srow >> 3)) & 7;
    const int sw1 = (((srow + 32) & 7) ^ ((srow + 32) >> 3)) & 7;
    const short* kbase = qkv + base + 1024 + h * 64;
    auto issueK = [&](int q, int k0) {
        gl2lds16(kbase + (long)(k0 + srow) * 3072      + (sg ^ sw0) * 8, sK[q] + tid * 8);
        gl2lds16(kbase + (long)(k0 + srow + 32) * 3072 + (sg ^ sw1) * 8, sK[q] + 2048 + tid * 8);
    };

    // V staging: pre-swizzled global source -> linear LDS (subtiled-for-tr layout)
    const int vslot   = (tid >> 3) & 7;
    const int vkbl    = 2 * (vslot & 3) + (vslot >> 2);
    const int vklocal = vkbl * 4 + ((tid >> 1) & 3);
    const short* vsrc = qkv + base + 2048 + h * 64
                      + (long)vklocal * 3072 + wave * 16 + 8 * (tid & 1);
    auto issueV = [&](int q, int k0) {
        gl2lds16(vsrc + (long)k0 * 3072,        sV[q] + tid * 8);        // ks=0 half
        gl2lds16(vsrc + (long)(k0 + 32) * 3072, sV[q] + 2048 + tid * 8); // ks=1 half
    };
    const unsigned trb = (unsigned)(unsigned long long)(&sV[0][0]) + (unsigned)lane * 8u;

    // swapped QK^T: st col = q (lane&15), row = key-local (quad*4+r)
    auto tile_step = [&](const s8x& qf0, const s8x& qf1, const s8x* kf0, const s8x* kf1,
                         const s8x (*vfr)[4], f32x4* o, float& lsum, int qt, int kt, int k0) {
        f32x4 s[4];
#pragma unroll
        for (int ct = 0; ct < 4; ++ct) {
            f32x4 t = f32x4{0.f, 0.f, 0.f, 0.f};
            t = __builtin_amdgcn_mfma_f32_16x16x32_bf16(kf0[ct], qf0, t, 0, 0, 0);
            t = __builtin_amdgcn_mfma_f32_16x16x32_bf16(kf1[ct], qf1, t, 0, 0, 0);
            s[ct] = t;
        }
        const int qrow = qt * 64 + wave * 16 + lrow;   // this lane's q
        float pv[4][4];
        if (kt == qt) {           // diagonal tile masking (uniform branch)
#pragma unroll
            for (int ct = 0; ct < 4; ++ct)
#pragma unroll
                for (int r = 0; r < 4; ++r) {
                    const int key = k0 + ct * 16 + quad * 4 + r;
                    const float pp = exp2f(fmaf(s[ct][r], ATT_CS, -ATT_C0));
                    const float pt = __uint_as_float(__float_as_uint(pp) & 0xFFFF0000u);
                    pv[ct][r] = (key > qrow) ? 0.f : pt;
                }
        } else {
#pragma unroll
            for (int ct = 0; ct < 4; ++ct)
#pragma unroll
                for (int r = 0; r < 4; ++r) {
                    const float pp = exp2f(fmaf(s[ct][r], ATT_CS, -ATT_C0));
                    pv[ct][r] = __uint_as_float(__float_as_uint(pp) & 0xFFFF0000u);
                }
        }
#pragma unroll
        for (int ct = 0; ct < 4; ++ct)
            lsum += (pv[ct][0] + pv[ct][1]) + (pv[ct][2] + pv[ct][3]);

        // pack P -> bf16 pairs: w2[ct][p] = keys {ct*16+4*quad+2p, +1} for q=lrow
        unsigned int w2[4][2];
#pragma unroll
        for (int ct = 0; ct < 4; ++ct)
#pragma unroll
            for (int p2 = 0; p2 < 2; ++p2)
                w2[ct][p2] = __builtin_amdgcn_perm(__float_as_uint(pv[ct][2 * p2 + 1]),
                                                   __float_as_uint(pv[ct][2 * p2]), 0x07060302u);
        // PV A-frag (lane needs P[q=lane&15][k=quad*8+e], e=0..7) via lane swaps
        s8x pa[2];
#pragma unroll
        for (int ks = 0; ks < 2; ++ks) {
            auto rAC = __builtin_amdgcn_permlane32_swap((int)w2[2 * ks][0], (int)w2[2 * ks + 1][0], false, false);
            auto rBD = __builtin_amdgcn_permlane32_swap((int)w2[2 * ks][1], (int)w2[2 * ks + 1][1], false, false);
            auto mAC = __builtin_amdgcn_permlane16_swap(rAC[0], rAC[1], false, false);
            auto mBD = __builtin_amdgcn_permlane16_swap(rBD[0], rBD[1], false, false);
            int4 f;
            f.x = mAC[0]; f.y = mBD[0]; f.z = mAC[1]; f.w = mBD[1];
            pa[ks] = *(const s8x*)&f;
        }
#pragma unroll
        for (int ks = 0; ks < 2; ++ks)
#pragma unroll
            for (int dt = 0; dt < 4; ++dt)
                o[dt] = __builtin_amdgcn_mfma_f32_16x16x32_bf16(pa[ks], vfr[ks][dt], o[dt], 0, 0, 0);
    };

    issueK(0, 0);   issueV(0, 0);
    issueK(1, 64);  issueV(1, 64);   // qtB >= 16: tile 1 always exists
    int cur = 0, nx2 = 2;
    for (int kt = 0; kt <= qtB; ++kt) {
        const int k0 = kt * 64;
        if (kt < qtB) { WAITV(4); } else { WAITV(0); }   // tile kt resident
        block_sync();
        if (kt + 2 <= qtB) { issueK(nx2, k0 + 128); issueV(nx2, k0 + 128); }

        // K fragments (compiler-managed LDS reads)
        s8x kf0[4], kf1[4];
#pragma unroll
        for (int ct = 0; ct < 4; ++ct) {
            const int row = ct * 16 + lrow;
            const int swr = ((row & 7) ^ (row >> 3)) & 7;
            kf0[ct] = *(const s8x*)(sK[cur] + row * 64 + ((quad ^ swr) * 8));
            kf1[ct] = *(const s8x*)(sK[cur] + row * 64 + (((4 + quad) ^ swr) * 8));
        }

        // V fragments via hw transpose reads (shared by both q-tiles)
        const unsigned tva = trb + (unsigned)(cur << 13);
        i32x2 tr[16];
        TR16(tr[0],  "0");    TR16(tr[1],  "512");
        TR16(tr[2],  "1024"); TR16(tr[3],  "1536");
        TR16(tr[4],  "2048"); TR16(tr[5],  "2560");
        TR16(tr[6],  "3072"); TR16(tr[7],  "3584");
        TR16(tr[8],  "4096"); TR16(tr[9],  "4608");
        TR16(tr[10], "5120"); TR16(tr[11], "5632");
        TR16(tr[12], "6144"); TR16(tr[13], "6656");
        TR16(tr[14], "7168"); TR16(tr[15], "7680");
        asm volatile("s_waitcnt lgkmcnt(0)" ::: "memory");
        __builtin_amdgcn_sched_barrier(0);       // rule #18: pin MFMAs after the wait
        s8x vfr[2][4];
#pragma unroll
        for (int ks = 0; ks < 2; ++ks)
#pragma unroll
            for (int dt = 0; dt < 4; ++dt) {
                const int i2 = ks * 8 + dt * 2;
                int4 f;
                f.x = tr[i2][0]; f.y = tr[i2][1];
                f.z = tr[i2 + 1][0]; f.w = tr[i2 + 1][1];
                vfr[ks][dt] = *(const s8x*)&f;
            }

        if (kt <= qtA) tile_step(qfA0, qfA1, kf0, kf1, vfr, oA, lA, qtA, kt, k0);
        tile_step(qfB0, qfB1, kf0, kf1, vfr, oB, lB, qtB, kt, k0);

        cur = (cur == 2) ? 0 : cur + 1;
        nx2 = (nx2 == 2) ? 0 : nx2 + 1;
    }

    // l lives per-lane at q=lane&15: reduce across quads, redistribute to C rows
    lA += __shfl_xor(lA, 16, 64); lA += __shfl_xor(lA, 32, 64);
    lB += __shfl_xor(lB, 16, 64); lB += __shfl_xor(lB, 32, 64);
    float rA[4], rB[4];
#pragma unroll
    for (int r = 0; r < 4; ++r) {
        rA[r] = 1.0f / __shfl(lA, quad * 4 + r, 64);
        rB[r] = 1.0f / __shfl(lB, quad * 4 + r, 64);
    }
#pragma unroll
    for (int dt = 0; dt < 4; ++dt) {
#pragma unroll
        for (int r = 0; r < 4; ++r) {
            const int qA = qtA * 64 + wave * 16 + quad * 4 + r;
            const int qB = qtB * 64 + wave * 16 + quad * 4 + r;
            y[((long)b * 2048 + qA) * 1024 + h * 64 + dt * 16 + lrow] = f2bf(oA[dt][r] * rA[r]);
            y[((long)b * 2048 + qB) * 1024 + h * 64 + dt * 16 + lrow] = f2bf(oB[dt][r] * rB[r]);
        }
    }
}

// ---------- launch ----------
extern "C" void kernel_launch(void* const* d_in, const int* in_sizes, int n_in,
                              void* d_out, int out_size, void* d_ws, size_t ws_size,
                              hipStream_t stream) {
    const float* x      = (const float*)d_in[0];
    const float* ln1_w  = (const float*)d_in[1];
    const float* ln1_b  = (const float*)d_in[2];
    const float* attn_w = (const float*)d_in[3];
    const float* attn_b = (const float*)d_in[4];
    const float* proj_w = (const float*)d_in[5];
    const float* proj_b = (const float*)d_in[6];
    const float* ln2_w  = (const float*)d_in[7];
    const float* ln2_b  = (const float*)d_in[8];
    const float* fc_w   = (const float*)d_in[9];
    const float* fc_b   = (const float*)d_in[10];
    const float* mlp_w  = (const float*)d_in[11];
    const float* mlp_b  = (const float*)d_in[12];

    char* ws = (char*)d_ws;
    short* attn_wt = (short*)(ws + 0);           // [3072,1024] bf16
    short* proj_wt = (short*)(ws + 6291456L);    // [1024,1024] bf16
    short* fc_wt   = (short*)(ws + 8388608L);    // [4096,1024] bf16
    short* mlp_wt  = (short*)(ws + 16777216L);   // [1024,4096] bf16
    short* slotA   = (short*)(ws + 25165824L);   // xln / y / h  [4096,1024] bf16
    short* slotB   = (short*)(ws + 33554432L);   // qkv [4096,3072] / hh [4096,4096] bf16
    // total ws use: 67,108,864 bytes (64 MB)

    short* xln  = slotA;
    short* yb   = slotA;
    short* hb   = slotA;
    short* qkvb = slotB;
    short* hh   = slotB;
    float* x1   = (float*)d_out;   // f32 residual stream lives in d_out
    float* outp = (float*)d_out;

    // transposes + LN1 fused (independent inputs)
    pre_k<<<13312, 256, 0, stream>>>(attn_w, proj_w, fc_w, mlp_w,
                                     attn_wt, proj_wt, fc_wt, mlp_wt,
                                     x, ln1_w, ln1_b, xln);

    gemm_k<0, short><<<dim3(24, 32), 256, 0, stream>>>(xln, attn_wt, attn_b, nullptr, qkvb, 4096, 3072, 1024);
    attn_k<<<dim3(16, 32), 256, 0, stream>>>(qkvb, yb);
    gemm128x64_k<2, float><<<dim3(16, 32), 256, 0, stream>>>(yb, proj_wt, proj_b, x, x1, 4096, 1024, 1024);
    ln_k<<<1024, 256, 0, stream>>>(x1, ln2_w, ln2_b, hb);
    gemm_k<1, short><<<dim3(32, 32), 256, 0, stream>>>(hb, fc_wt, fc_b, nullptr, hh, 4096, 4096, 1024);
    gemm128x64_k<3, float><<<dim3(16, 32), 256, 0, stream>>>(hh, mlp_wt, mlp_b, x1, outp, 4096, 1024, 4096);
}

// Round 13
// 326.913 us; speedup vs baseline: 1.0387x; 1.0094x over previous
//
#include <hip/hip_runtime.h>
#include <math.h>

// ---------- types / helpers ----------
typedef short s8x __attribute__((ext_vector_type(8)));    // 8 bf16 (4 VGPRs) MFMA A/B frag
typedef float f32x4 __attribute__((ext_vector_type(4)));  // 16x16 MFMA C/D frag
typedef int   i32x2 __attribute__((ext_vector_type(2)));  // 64-bit tr-read result

__device__ __forceinline__ float bf2f(short u) {
    return __uint_as_float(((unsigned int)(unsigned short)u) << 16);
}
__device__ __forceinline__ short f2bf(float f) {
    unsigned int x = __float_as_uint(f);
    unsigned int r = (x + 0x7FFFu + ((x >> 16) & 1u)) >> 16; // RNE
    return (short)(unsigned short)r;
}

// async global->LDS, 16B per lane. LDS dest must be wave-uniform base + lane*16.
__device__ __forceinline__ void gl2lds16(const short* g, const short* l) {
    __builtin_amdgcn_global_load_lds(
        (const __attribute__((address_space(1))) void*)(unsigned long long)g,
        (__attribute__((address_space(3))) void*)(unsigned int)(unsigned long long)l,
        16, 0, 0);
}

// raw barrier with compiler memory fences (no vmcnt(0) drain, unlike __syncthreads)
__device__ __forceinline__ void block_sync() {
    asm volatile("" ::: "memory");
    __builtin_amdgcn_s_barrier();
    asm volatile("" ::: "memory");
}
#define WAITV(n) asm volatile("s_waitcnt vmcnt(" #n ")" ::: "memory")

// ---------- wave-per-row LayerNorm core: f32 in -> bf16 out, C=1024 ----------
__device__ __forceinline__ void ln_row(const float* __restrict__ xin,
                                       const float* __restrict__ w,
                                       const float* __restrict__ bb,
                                       short* __restrict__ out, int row, int lane) {
    const float4* xr = (const float4*)(xin + (long)row * 1024);
    float4 v[4];
    float s1 = 0.f, s2 = 0.f;
#pragma unroll
    for (int i = 0; i < 4; ++i) {
        v[i] = xr[lane + i * 64];
        s1 += v[i].x + v[i].y + v[i].z + v[i].w;
        s2 += v[i].x*v[i].x + v[i].y*v[i].y + v[i].z*v[i].z + v[i].w*v[i].w;
    }
#pragma unroll
    for (int off = 32; off > 0; off >>= 1) {
        s1 += __shfl_xor(s1, off, 64);
        s2 += __shfl_xor(s2, off, 64);
    }
    const float mu = s1 * (1.0f / 1024.0f);
    float var = s2 * (1.0f / 1024.0f) - mu * mu;
    var = fmaxf(var, 0.0f);
    const float rs = rsqrtf(var + 1e-5f);
    short4* orow = (short4*)(out + (long)row * 1024);
#pragma unroll
    for (int i = 0; i < 4; ++i) {
        const int ci = (lane + i * 64) * 4;
        const float4 wv = *(const float4*)(w + ci);
        const float4 bv = *(const float4*)(bb + ci);
        short4 o;
        o.x = f2bf((v[i].x - mu) * rs * wv.x + bv.x);
        o.y = f2bf((v[i].y - mu) * rs * wv.y + bv.y);
        o.z = f2bf((v[i].z - mu) * rs * wv.z + bv.z);
        o.w = f2bf((v[i].w - mu) * rs * wv.w + bv.w);
        orow[lane + i * 64] = o;
    }
}

__global__ __launch_bounds__(256) void ln_k(const float* __restrict__ xin,
                                            const float* __restrict__ w,
                                            const float* __restrict__ bb,
                                            short* __restrict__ out) {
    ln_row(xin, w, bb, out, blockIdx.x * 4 + (threadIdx.x >> 6), threadIdx.x & 63);
}

// ---------- fused: 4 weight transposes (f32 [K][N] -> bf16 [N][K]) + LN1 ----------
__global__ __launch_bounds__(256) void pre_k(
        const float* __restrict__ w0, const float* __restrict__ w1,
        const float* __restrict__ w2, const float* __restrict__ w3,
        short* __restrict__ o0, short* __restrict__ o1,
        short* __restrict__ o2, short* __restrict__ o3,
        const float* __restrict__ x, const float* __restrict__ ln1w,
        const float* __restrict__ ln1b, short* __restrict__ xln) {
    int bid = blockIdx.x;
    if (bid >= 12288) {   // LN1: 1024 blocks, 4 rows each (wave per row)
        ln_row(x, ln1w, ln1b, xln, (bid - 12288) * 4 + (threadIdx.x >> 6), threadIdx.x & 63);
        return;
    }
    const float* in; short* out; int K, N, nx;
    if (bid < 3072)      { in = w0; out = o0; K = 1024; N = 3072; nx = 96; }
    else if (bid < 4096) { bid -= 3072; in = w1; out = o1; K = 1024; N = 1024; nx = 32; }
    else if (bid < 8192) { bid -= 4096; in = w2; out = o2; K = 1024; N = 4096; nx = 128; }
    else                 { bid -= 8192; in = w3; out = o3; K = 4096; N = 1024; nx = 32; }
    const int n0 = (bid % nx) * 32, k0 = (bid / nx) * 32;
    __shared__ float tile[32][33];
    const int tx = threadIdx.x & 31, ty = threadIdx.x >> 5; // ty 0..7
#pragma unroll
    for (int i = 0; i < 4; ++i) {
        const int k = ty + i * 8;
        tile[k][tx] = in[(long)(k0 + k) * N + n0 + tx];
    }
    __syncthreads();
#pragma unroll
    for (int i = 0; i < 4; ++i) {
        const int n = ty + i * 8;
        out[(long)(n0 + n) * K + k0 + tx] = f2bf(tile[tx][n]);
    }
}

// ---------- GEMM epilogue ----------
// EPI 1 GELU: tanh-form (sigmoid identity), |delta vs exact erf| < 3e-3 << bf16 tol.
template <int EPI, typename OutT>
__device__ __forceinline__ void epi_store(OutT* out, const float* resid, long oidx, float v) {
    if constexpr (EPI == 0) {
        out[oidx] = f2bf(v);
    } else if constexpr (EPI == 1) {
        const float u = v * (0.79788456080f + 0.03567740814f * v * v);
        v = v / (1.0f + __expf(-2.0f * u));
        out[oidx] = f2bf(v);
    } else {
        v += resid[oidx];
        out[oidx] = v;   // f32 store
    }
}

// ---------- GEMM 128x128, BK=32, TRIPLE-buffered, counted vmcnt, 1 barrier/step ----------
// LDS = 48 KB. Tile s+2 stages into buf (s+2)%3 == (s-1)%3, whose ds_reads all
// completed (they feed the pre-barrier MFMAs via compiler lgkmcnt waits) before
// any wave passed THIS barrier -> no WAR hazard, no second barrier. WAITV(4):
// tile s resident, tile s+1's 4 loads stay in flight across the barrier.
// NO XCD swizzle: measured FETCH 41->97 MB with chunked swizzle at gx=32
// (per-XCD B working set exceeds 4 MB L2); natural mapping is better here.
template <int EPI, typename OutT>
__global__ __launch_bounds__(256) void gemm_k(const short* __restrict__ A,
                                              const short* __restrict__ Bt,
                                              const float* __restrict__ bias,
                                              const float* __restrict__ resid,
                                              OutT* __restrict__ out,
                                              int M, int N, int K) {
    __shared__ __align__(16) short sA[3][128 * 32];
    __shared__ __align__(16) short sB[3][128 * 32];
    const int tid = threadIdx.x;
    const int lane = tid & 63, wave = tid >> 6;
    const int wr = (wave >> 1) * 64, wc = (wave & 1) * 64;
    const int lrow = lane & 15, quad = lane >> 4;
    const int bm = blockIdx.y * 128, bn = blockIdx.x * 128;
    const short* Ap = A + (long)(bm + (tid >> 2)) * K + (tid & 3) * 8;
    const short* Bp = Bt + (long)(bn + (tid >> 2)) * K + (tid & 3) * 8;
    const long rowstep = (long)64 * K;

    auto stage = [&](int q, int k0) {
        gl2lds16(Ap + k0,           sA[q] + tid * 8);
        gl2lds16(Ap + rowstep + k0, sA[q] + 2048 + tid * 8);
        gl2lds16(Bp + k0,           sB[q] + tid * 8);
        gl2lds16(Bp + rowstep + k0, sB[q] + 2048 + tid * 8);
    };

    f32x4 acc[4][4] = {};
    const int S = K >> 5;
    stage(0, 0);
    stage(1, 32);
    int cur = 0, nx2 = 2;
    for (int s = 0; s < S; ++s) {
        if (s + 1 < S) { WAITV(4); } else { WAITV(0); }   // tile s resident
        block_sync();
        if (s + 2 < S) stage(nx2, (s + 2) << 5);          // writes buf (s-1)%3: safe
        const short* pA = sA[cur];
        const short* pB = sB[cur];
        s8x af[4], bfr[4];
#pragma unroll
        for (int i = 0; i < 4; ++i) af[i]  = *(const s8x*)(pA + (wr + i*16 + lrow) * 32 + quad * 8);
#pragma unroll
        for (int j = 0; j < 4; ++j) bfr[j] = *(const s8x*)(pB + (wc + j*16 + lrow) * 32 + quad * 8);
#pragma unroll
        for (int i = 0; i < 4; ++i)
#pragma unroll
            for (int j = 0; j < 4; ++j)
                acc[i][j] = __builtin_amdgcn_mfma_f32_16x16x32_bf16(af[i], bfr[j], acc[i][j], 0, 0, 0);
        cur = (cur == 2) ? 0 : cur + 1;
        nx2 = (nx2 == 2) ? 0 : nx2 + 1;
    }
#pragma unroll
    for (int i = 0; i < 4; ++i) {
#pragma unroll
        for (int j = 0; j < 4; ++j) {
#pragma unroll
            for (int r = 0; r < 4; ++r) {
                const int row = bm + wr + i*16 + quad*4 + r;   // C/D: row = quad*4 + reg
                const int col = bn + wc + j*16 + lrow;         // C/D: col = lane&15
                epi_store<EPI>(out, resid, (long)row * N + col, acc[i][j][r] + bias[col]);
            }
        }
    }
}

// ---------- GEMM 128x64, BK=64, TRIPLE-buffered, counted vmcnt, XCD-swizzled ----------
// 72 KB LDS (legal: gfx950 supports up to 160 KB/WG; the 8-phase reference
// template uses 128 KB static). Same single-barrier counted-vmcnt loop that
// took fc from 82.9 -> ~52 us: vmcnt(6) keeps tile s+1's loads in flight —
// the per-step vmcnt(0) drain of the 2-phase __syncthreads form is GONE.
// WAR-safe: buf (s+2)%3 was fully consumed before barrier s (same proof as
// gemm_k). XCD-chunked swizzle kept (measured FETCH 143->57 MB at gx=16).
template <int EPI, typename OutT>
__global__ __launch_bounds__(256) void gemm128x64_k(const short* __restrict__ A,
                                                    const short* __restrict__ Bt,
                                                    const float* __restrict__ bias,
                                                    const float* __restrict__ resid,
                                                    OutT* __restrict__ out,
                                                    int M, int N, int K) {
    __shared__ __align__(16) short sA[3][2][128 * 32];
    __shared__ __align__(16) short sB[3][2][64 * 32];
    const int tid = threadIdx.x;
    const int lane = tid & 63, wave = tid >> 6;
    const int wr = (wave >> 1) * 64, wc = (wave & 1) * 32;
    const int lrow = lane & 15, quad = lane >> 4;
    // XCD-chunked bijective swizzle (nwg = 512, %8 == 0)
    const int gx = gridDim.x;
    const int nwg = gx * gridDim.y;
    const int bid = blockIdx.y * gx + blockIdx.x;
    const int swz = (bid & 7) * (nwg >> 3) + (bid >> 3);
    const int bm = (swz / gx) * 128, bn = (swz % gx) * 64;
    const short* Ap = A + (long)(bm + (tid >> 2)) * K + (tid & 3) * 8;
    const short* Bp = Bt + (long)(bn + (tid >> 2)) * K + (tid & 3) * 8;
    const long rowstep = (long)64 * K;

    auto stage = [&](int q, int k0) {
#pragma unroll
        for (int hp = 0; hp < 2; ++hp) {
            gl2lds16(Ap + k0 + hp * 32,           sA[q][hp] + tid * 8);
            gl2lds16(Ap + rowstep + k0 + hp * 32, sA[q][hp] + 2048 + tid * 8);
            gl2lds16(Bp + k0 + hp * 32,           sB[q][hp] + tid * 8);
        }
    };

    f32x4 acc[4][2] = {};
    const int S = K >> 6;
    stage(0, 0);
    stage(1, 64);
    int cur = 0, nx2 = 2;
    for (int s = 0; s < S; ++s) {
        if (s + 1 < S) { WAITV(6); } else { WAITV(0); }   // tile s resident
        block_sync();
        if (s + 2 < S) stage(nx2, (s + 2) << 6);          // buf (s-1)%3: WAR-safe
#pragma unroll
        for (int hp = 0; hp < 2; ++hp) {
            s8x af[4], bfr[2];
#pragma unroll
            for (int i = 0; i < 4; ++i) af[i]  = *(const s8x*)(sA[cur][hp] + (wr + i*16 + lrow) * 32 + quad * 8);
#pragma unroll
            for (int j = 0; j < 2; ++j) bfr[j] = *(const s8x*)(sB[cur][hp] + (wc + j*16 + lrow) * 32 + quad * 8);
#pragma unroll
            for (int i = 0; i < 4; ++i)
#pragma unroll
                for (int j = 0; j < 2; ++j)
                    acc[i][j] = __builtin_amdgcn_mfma_f32_16x16x32_bf16(af[i], bfr[j], acc[i][j], 0, 0, 0);
        }
        cur = (cur == 2) ? 0 : cur + 1;
        nx2 = (nx2 == 2) ? 0 : nx2 + 1;
    }
#pragma unroll
    for (int i = 0; i < 4; ++i) {
#pragma unroll
        for (int j = 0; j < 2; ++j) {
#pragma unroll
            for (int r = 0; r < 4; ++r) {
                const int row = bm + wr + i*16 + quad*4 + r;
                const int col = bn + wc + j*16 + lrow;
                epi_store<EPI>(out, resid, (long)row * N + col, acc[i][j][r] + bias[col]);
            }
        }
    }
}

// ---------- attention common constants ----------
#define ATT_CS (0.125f * 1.4426950408889634f)  /* log2(e)/sqrt(64) */
#define ATT_C0 (14.426950408889634f)           /* 10*log2(e) fixed shift */

// hw transpose read: lane l receives column (l&15), rows j=0..3 of the [4][16]
// bf16 tile in the 128B window (l>>4); vaddr = base + lane*8B, offset literal.
#define TR16(dst, off) \
    asm volatile("ds_read_b64_tr_b16 %0, %1 offset:" off : "=v"(dst) : "v"(tva))

// ---------- paired-tile causal flash attention: B=2,H=16,T=2048,hs=64 ----------
// Pairs (bx, 31-bx): every block exactly 33 tile-iterations. Swapped QK^T
// (mfma(K,Q)) -> in-register softmax/l/pack + permlane rebuild of PV A-frag.
// V staged by direct global_load_lds DMA into tr_b16-compatible subtiled layout;
// PV B-frags via ds_read_b64_tr_b16 (shared by both q-tiles). Triple-buffered
// K/V (48 KB LDS) with counted vmcnt: next tile's loads fly across the barrier.
__global__ __launch_bounds__(256) void attn_k(const short* __restrict__ qkv,
                                              short* __restrict__ y) {
    const int bx = blockIdx.x;                 // 0..15
    const int b = blockIdx.y >> 4, h = blockIdx.y & 15;
    const int qtA = bx, qtB = 31 - bx;
    const int tid = threadIdx.x, lane = tid & 63, wave = tid >> 6;
    const int lrow = lane & 15, quad = lane >> 4;
    const long base = (long)b * 2048 * 3072;

    __shared__ __align__(16) short sK[3][64 * 64];
    __shared__ __align__(16) short sV[3][4096];

    s8x qfA0, qfA1, qfB0, qfB1;
    {
        const short* qpA = qkv + base + (long)(qtA * 64 + wave * 16 + lrow) * 3072 + h * 64 + quad * 8;
        qfA0 = *(const s8x*)qpA; qfA1 = *(const s8x*)(qpA + 32);
        const short* qpB = qkv + base + (long)(qtB * 64 + wave * 16 + lrow) * 3072 + h * 64 + quad * 8;
        qfB0 = *(const s8x*)qpB; qfB1 = *(const s8x*)(qpB + 32);
    }
    f32x4 oA[4], oB[4];
    float lA = 0.f, lB = 0.f;
#pragma unroll
    for (int d = 0; d < 4; ++d) { oA[d] = f32x4{0.f,0.f,0.f,0.f}; oB[d] = f32x4{0.f,0.f,0.f,0.f}; }

    // K staging (XOR-swizzled rows)
    const int srow = tid >> 3, sg = tid & 7;
    const int sw0 = ((srow & 7) ^ (srow >> 3)) & 7;
    const int sw1 = (((srow + 32) & 7) ^ ((srow + 32) >> 3)) & 7;
    const short* kbase = qkv + base + 1024 + h * 64;
    auto issueK = [&](int q, int k0) {
        gl2lds16(kbase + (long)(k0 + srow) * 3072      + (sg ^ sw0) * 8, sK[q] + tid * 8);
        gl2lds16(kbase + (long)(k0 + srow + 32) * 3072 + (sg ^ sw1) * 8, sK[q] + 2048 + tid * 8);
    };

    // V staging: pre-swizzled global source -> linear LDS (subtiled-for-tr layout)
    const int vslot   = (tid >> 3) & 7;
    const int vkbl    = 2 * (vslot & 3) + (vslot >> 2);
    const int vklocal = vkbl * 4 + ((tid >> 1) & 3);
    const short* vsrc = qkv + base + 2048 + h * 64
                      + (long)vklocal * 3072 + wave * 16 + 8 * (tid & 1);
    auto issueV = [&](int q, int k0) {
        gl2lds16(vsrc + (long)k0 * 3072,        sV[q] + tid * 8);        // ks=0 half
        gl2lds16(vsrc + (long)(k0 + 32) * 3072, sV[q] + 2048 + tid * 8); // ks=1 half
    };
    const unsigned trb = (unsigned)(unsigned long long)(&sV[0][0]) + (unsigned)lane * 8u;

    // swapped QK^T: st col = q (lane&15), row = key-local (quad*4+r)
    auto tile_step = [&](const s8x& qf0, const s8x& qf1, const s8x* kf0, const s8x* kf1,
                         const s8x (*vfr)[4], f32x4* o, float& lsum, int qt, int kt, int k0) {
        f32x4 s[4];
#pragma unroll
        for (int ct = 0; ct < 4; ++ct) {
            f32x4 t = f32x4{0.f, 0.f, 0.f, 0.f};
            t = __builtin_amdgcn_mfma_f32_16x16x32_bf16(kf0[ct], qf0, t, 0, 0, 0);
            t = __builtin_amdgcn_mfma_f32_16x16x32_bf16(kf1[ct], qf1, t, 0, 0, 0);
            s[ct] = t;
        }
        const int qrow = qt * 64 + wave * 16 + lrow;   // this lane's q
        float pv[4][4];
        if (kt == qt) {           // diagonal tile masking (uniform branch)
#pragma unroll
            for (int ct = 0; ct < 4; ++ct)
#pragma unroll
                for (int r = 0; r < 4; ++r) {
                    const int key = k0 + ct * 16 + quad * 4 + r;
                    const float pp = exp2f(fmaf(s[ct][r], ATT_CS, -ATT_C0));
                    const float pt = __uint_as_float(__float_as_uint(pp) & 0xFFFF0000u);
                    pv[ct][r] = (key > qrow) ? 0.f : pt;
                }
        } else {
#pragma unroll
            for (int ct = 0; ct < 4; ++ct)
#pragma unroll
                for (int r = 0; r < 4; ++r) {
                    const float pp = exp2f(fmaf(s[ct][r], ATT_CS, -ATT_C0));
                    pv[ct][r] = __uint_as_float(__float_as_uint(pp) & 0xFFFF0000u);
                }
        }
#pragma unroll
        for (int ct = 0; ct < 4; ++ct)
            lsum += (pv[ct][0] + pv[ct][1]) + (pv[ct][2] + pv[ct][3]);

        // pack P -> bf16 pairs: w2[ct][p] = keys {ct*16+4*quad+2p, +1} for q=lrow
        unsigned int w2[4][2];
#pragma unroll
        for (int ct = 0; ct < 4; ++ct)
#pragma unroll
            for (int p2 = 0; p2 < 2; ++p2)
                w2[ct][p2] = __builtin_amdgcn_perm(__float_as_uint(pv[ct][2 * p2 + 1]),
                                                   __float_as_uint(pv[ct][2 * p2]), 0x07060302u);
        // PV A-frag (lane needs P[q=lane&15][k=quad*8+e], e=0..7) via lane swaps
        s8x pa[2];
#pragma unroll
        for (int ks = 0; ks < 2; ++ks) {
            auto rAC = __builtin_amdgcn_permlane32_swap((int)w2[2 * ks][0], (int)w2[2 * ks + 1][0], false, false);
            auto rBD = __builtin_amdgcn_permlane32_swap((int)w2[2 * ks][1], (int)w2[2 * ks + 1][1], false, false);
            auto mAC = __builtin_amdgcn_permlane16_swap(rAC[0], rAC[1], false, false);
            auto mBD = __builtin_amdgcn_permlane16_swap(rBD[0], rBD[1], false, false);
            int4 f;
            f.x = mAC[0]; f.y = mBD[0]; f.z = mAC[1]; f.w = mBD[1];
            pa[ks] = *(const s8x*)&f;
        }
#pragma unroll
        for (int ks = 0; ks < 2; ++ks)
#pragma unroll
            for (int dt = 0; dt < 4; ++dt)
                o[dt] = __builtin_amdgcn_mfma_f32_16x16x32_bf16(pa[ks], vfr[ks][dt], o[dt], 0, 0, 0);
    };

    issueK(0, 0);   issueV(0, 0);
    issueK(1, 64);  issueV(1, 64);   // qtB >= 16: tile 1 always exists
    int cur = 0, nx2 = 2;
    for (int kt = 0; kt <= qtB; ++kt) {
        const int k0 = kt * 64;
        if (kt < qtB) { WAITV(4); } else { WAITV(0); }   // tile kt resident
        block_sync();
        if (kt + 2 <= qtB) { issueK(nx2, k0 + 128); issueV(nx2, k0 + 128); }

        // K fragments (compiler-managed LDS reads)
        s8x kf0[4], kf1[4];
#pragma unroll
        for (int ct = 0; ct < 4; ++ct) {
            const int row = ct * 16 + lrow;
            const int swr = ((row & 7) ^ (row >> 3)) & 7;
            kf0[ct] = *(const s8x*)(sK[cur] + row * 64 + ((quad ^ swr) * 8));
            kf1[ct] = *(const s8x*)(sK[cur] + row * 64 + (((4 + quad) ^ swr) * 8));
        }

        // V fragments via hw transpose reads (shared by both q-tiles)
        const unsigned tva = trb + (unsigned)(cur << 13);
        i32x2 tr[16];
        TR16(tr[0],  "0");    TR16(tr[1],  "512");
        TR16(tr[2],  "1024"); TR16(tr[3],  "1536");
        TR16(tr[4],  "2048"); TR16(tr[5],  "2560");
        TR16(tr[6],  "3072"); TR16(tr[7],  "3584");
        TR16(tr[8],  "4096"); TR16(tr[9],  "4608");
        TR16(tr[10], "5120"); TR16(tr[11], "5632");
        TR16(tr[12], "6144"); TR16(tr[13], "6656");
        TR16(tr[14], "7168"); TR16(tr[15], "7680");
        asm volatile("s_waitcnt lgkmcnt(0)" ::: "memory");
        __builtin_amdgcn_sched_barrier(0);       // rule #18: pin MFMAs after the wait
        s8x vfr[2][4];
#pragma unroll
        for (int ks = 0; ks < 2; ++ks)
#pragma unroll
            for (int dt = 0; dt < 4; ++dt) {
                const int i2 = ks * 8 + dt * 2;
                int4 f;
                f.x = tr[i2][0]; f.y = tr[i2][1];
                f.z = tr[i2 + 1][0]; f.w = tr[i2 + 1][1];
                vfr[ks][dt] = *(const s8x*)&f;
            }

        if (kt <= qtA) tile_step(qfA0, qfA1, kf0, kf1, vfr, oA, lA, qtA, kt, k0);
        tile_step(qfB0, qfB1, kf0, kf1, vfr, oB, lB, qtB, kt, k0);

        cur = (cur == 2) ? 0 : cur + 1;
        nx2 = (nx2 == 2) ? 0 : nx2 + 1;
    }

    // l lives per-lane at q=lane&15: reduce across quads, redistribute to C rows
    lA += __shfl_xor(lA, 16, 64); lA += __shfl_xor(lA, 32, 64);
    lB += __shfl_xor(lB, 16, 64); lB += __shfl_xor(lB, 32, 64);
    float rA[4], rB[4];
#pragma unroll
    for (int r = 0; r < 4; ++r) {
        rA[r] = 1.0f / __shfl(lA, quad * 4 + r, 64);
        rB[r] = 1.0f / __shfl(lB, quad * 4 + r, 64);
    }
#pragma unroll
    for (int dt = 0; dt < 4; ++dt) {
#pragma unroll
        for (int r = 0; r < 4; ++r) {
            const int qA = qtA * 64 + wave * 16 + quad * 4 + r;
            const int qB = qtB * 64 + wave * 16 + quad * 4 + r;
            y[((long)b * 2048 + qA) * 1024 + h * 64 + dt * 16 + lrow] = f2bf(oA[dt][r] * rA[r]);
            y[((long)b * 2048 + qB) * 1024 + h * 64 + dt * 16 + lrow] = f2bf(oB[dt][r] * rB[r]);
        }
    }
}

// ---------- launch ----------
extern "C" void kernel_launch(void* const* d_in, const int* in_sizes, int n_in,
                              void* d_out, int out_size, void* d_ws, size_t ws_size,
                              hipStream_t stream) {
    const float* x      = (const float*)d_in[0];
    const float* ln1_w  = (const float*)d_in[1];
    const float* ln1_b  = (const float*)d_in[2];
    const float* attn_w = (const float*)d_in[3];
    const float* attn_b = (const float*)d_in[4];
    const float* proj_w = (const float*)d_in[5];
    const float* proj_b = (const float*)d_in[6];
    const float* ln2_w  = (const float*)d_in[7];
    const float* ln2_b  = (const float*)d_in[8];
    const float* fc_w   = (const float*)d_in[9];
    const float* fc_b   = (const float*)d_in[10];
    const float* mlp_w  = (const float*)d_in[11];
    const float* mlp_b  = (const float*)d_in[12];

    char* ws = (char*)d_ws;
    short* attn_wt = (short*)(ws + 0);           // [3072,1024] bf16
    short* proj_wt = (short*)(ws + 6291456L);    // [1024,1024] bf16
    short* fc_wt   = (short*)(ws + 8388608L);    // [4096,1024] bf16
    short* mlp_wt  = (short*)(ws + 16777216L);   // [1024,4096] bf16
    short* slotA   = (short*)(ws + 25165824L);   // xln / y / h  [4096,1024] bf16
    short* slotB   = (short*)(ws + 33554432L);   // qkv [4096,3072] / hh [4096,4096] bf16
    // total ws use: 67,108,864 bytes (64 MB)

    short* xln  = slotA;
    short* yb   = slotA;
    short* hb   = slotA;
    short* qkvb = slotB;
    short* hh   = slotB;
    float* x1   = (float*)d_out;   // f32 residual stream lives in d_out
    float* outp = (float*)d_out;

    // transposes + LN1 fused (independent inputs)
    pre_k<<<13312, 256, 0, stream>>>(attn_w, proj_w, fc_w, mlp_w,
                                     attn_wt, proj_wt, fc_wt, mlp_wt,
                                     x, ln1_w, ln1_b, xln);

    gemm_k<0, short><<<dim3(24, 32), 256, 0, stream>>>(xln, attn_wt, attn_b, nullptr, qkvb, 4096, 3072, 1024);
    attn_k<<<dim3(16, 32), 256, 0, stream>>>(qkvb, yb);
    gemm128x64_k<2, float><<<dim3(16, 32), 256, 0, stream>>>(yb, proj_wt, proj_b, x, x1, 4096, 1024, 1024);
    ln_k<<<1024, 256, 0, stream>>>(x1, ln2_w, ln2_b, hb);
    gemm_k<1, short><<<dim3(32, 32), 256, 0, stream>>>(hb, fc_wt, fc_b, nullptr, hh, 4096, 4096, 1024);
    gemm128x64_k<3, float><<<dim3(16, 32), 256, 0, stream>>>(hh, mlp_wt, mlp_b, x1, outp, 4096, 1024, 4096);
}

// Round 14
// 325.079 us; speedup vs baseline: 1.0445x; 1.0056x over previous
//
#include <hip/hip_runtime.h>
#include <math.h>

// ---------- types / helpers ----------
typedef short s8x __attribute__((ext_vector_type(8)));    // 8 bf16 (4 VGPRs) MFMA A/B frag
typedef float f32x4 __attribute__((ext_vector_type(4)));  // 16x16 MFMA C/D frag
typedef int   i32x2 __attribute__((ext_vector_type(2)));  // 64-bit tr-read result

__device__ __forceinline__ float bf2f(short u) {
    return __uint_as_float(((unsigned int)(unsigned short)u) << 16);
}
__device__ __forceinline__ short f2bf(float f) {
    unsigned int x = __float_as_uint(f);
    unsigned int r = (x + 0x7FFFu + ((x >> 16) & 1u)) >> 16; // RNE
    return (short)(unsigned short)r;
}

// async global->LDS, 16B per lane. LDS dest must be wave-uniform base + lane*16.
__device__ __forceinline__ void gl2lds16(const short* g, const short* l) {
    __builtin_amdgcn_global_load_lds(
        (const __attribute__((address_space(1))) void*)(unsigned long long)g,
        (__attribute__((address_space(3))) void*)(unsigned int)(unsigned long long)l,
        16, 0, 0);
}

// raw barrier with compiler memory fences (no vmcnt(0) drain, unlike __syncthreads)
__device__ __forceinline__ void block_sync() {
    asm volatile("" ::: "memory");
    __builtin_amdgcn_s_barrier();
    asm volatile("" ::: "memory");
}
#define WAITV(n) asm volatile("s_waitcnt vmcnt(" #n ")" ::: "memory")

// ---------- wave-per-row LayerNorm core: f32 in -> bf16 out, C=1024 ----------
__device__ __forceinline__ void ln_row(const float* __restrict__ xin,
                                       const float* __restrict__ w,
                                       const float* __restrict__ bb,
                                       short* __restrict__ out, int row, int lane) {
    const float4* xr = (const float4*)(xin + (long)row * 1024);
    float4 v[4];
    float s1 = 0.f, s2 = 0.f;
#pragma unroll
    for (int i = 0; i < 4; ++i) {
        v[i] = xr[lane + i * 64];
        s1 += v[i].x + v[i].y + v[i].z + v[i].w;
        s2 += v[i].x*v[i].x + v[i].y*v[i].y + v[i].z*v[i].z + v[i].w*v[i].w;
    }
#pragma unroll
    for (int off = 32; off > 0; off >>= 1) {
        s1 += __shfl_xor(s1, off, 64);
        s2 += __shfl_xor(s2, off, 64);
    }
    const float mu = s1 * (1.0f / 1024.0f);
    float var = s2 * (1.0f / 1024.0f) - mu * mu;
    var = fmaxf(var, 0.0f);
    const float rs = rsqrtf(var + 1e-5f);
    short4* orow = (short4*)(out + (long)row * 1024);
#pragma unroll
    for (int i = 0; i < 4; ++i) {
        const int ci = (lane + i * 64) * 4;
        const float4 wv = *(const float4*)(w + ci);
        const float4 bv = *(const float4*)(bb + ci);
        short4 o;
        o.x = f2bf((v[i].x - mu) * rs * wv.x + bv.x);
        o.y = f2bf((v[i].y - mu) * rs * wv.y + bv.y);
        o.z = f2bf((v[i].z - mu) * rs * wv.z + bv.z);
        o.w = f2bf((v[i].w - mu) * rs * wv.w + bv.w);
        orow[lane + i * 64] = o;
    }
}

__global__ __launch_bounds__(256) void ln_k(const float* __restrict__ xin,
                                            const float* __restrict__ w,
                                            const float* __restrict__ bb,
                                            short* __restrict__ out) {
    ln_row(xin, w, bb, out, blockIdx.x * 4 + (threadIdx.x >> 6), threadIdx.x & 63);
}

// ---------- fused: 4 weight transposes (f32 [K][N] -> bf16 [N][K]) + LN1 ----------
// 64x64 tiles, float4 reads (1 KB/wave-instr) + short4 writes (512 B/wave-instr);
// LDS [64][65] pad keeps both phases <=2-way bank aliasing (free). Replaces the
// old 32x32 form whose bf16 writes were 64 B segments (half-coalesced).
__global__ __launch_bounds__(256) void pre_k(
        const float* __restrict__ w0, const float* __restrict__ w1,
        const float* __restrict__ w2, const float* __restrict__ w3,
        short* __restrict__ o0, short* __restrict__ o1,
        short* __restrict__ o2, short* __restrict__ o3,
        const float* __restrict__ x, const float* __restrict__ ln1w,
        const float* __restrict__ ln1b, short* __restrict__ xln) {
    int bid = blockIdx.x;
    if (bid >= 3072) {   // LN1: 1024 blocks, 4 rows each (wave per row)
        ln_row(x, ln1w, ln1b, xln, (bid - 3072) * 4 + (threadIdx.x >> 6), threadIdx.x & 63);
        return;
    }
    const float* in; short* out; int K, N, nx;
    if (bid < 768)       { in = w0; out = o0; K = 1024; N = 3072; nx = 48; }
    else if (bid < 1024) { bid -= 768;  in = w1; out = o1; K = 1024; N = 1024; nx = 16; }
    else if (bid < 2048) { bid -= 1024; in = w2; out = o2; K = 1024; N = 4096; nx = 64; }
    else                 { bid -= 2048; in = w3; out = o3; K = 4096; N = 1024; nx = 16; }
    const int n0 = (bid % nx) * 64, k0 = (bid / nx) * 64;
    __shared__ float tile[64][65];
    const int tx = threadIdx.x & 15, ty = threadIdx.x >> 4;  // ty 0..15
#pragma unroll
    for (int p = 0; p < 4; ++p) {
        const int k = p * 16 + ty;
        const float4 v = *(const float4*)(in + (long)(k0 + k) * N + n0 + tx * 4);
        tile[k][tx * 4 + 0] = v.x;
        tile[k][tx * 4 + 1] = v.y;
        tile[k][tx * 4 + 2] = v.z;
        tile[k][tx * 4 + 3] = v.w;
    }
    __syncthreads();
#pragma unroll
    for (int p = 0; p < 4; ++p) {
        const int n = p * 16 + ty;
        short4 o;
        o.x = f2bf(tile[tx * 4 + 0][n]);
        o.y = f2bf(tile[tx * 4 + 1][n]);
        o.z = f2bf(tile[tx * 4 + 2][n]);
        o.w = f2bf(tile[tx * 4 + 3][n]);
        *(short4*)(out + (long)(n0 + n) * K + k0 + tx * 4) = o;
    }
}

// ---------- GEMM epilogue ----------
// EPI 1 GELU: tanh-form (sigmoid identity), |delta vs exact erf| < 3e-3 << bf16 tol.
template <int EPI, typename OutT>
__device__ __forceinline__ void epi_store(OutT* out, const float* resid, long oidx, float v) {
    if constexpr (EPI == 0) {
        out[oidx] = f2bf(v);
    } else if constexpr (EPI == 1) {
        const float u = v * (0.79788456080f + 0.03567740814f * v * v);
        v = v / (1.0f + __expf(-2.0f * u));
        out[oidx] = f2bf(v);
    } else {
        v += resid[oidx];
        out[oidx] = v;   // f32 store
    }
}

// ---------- GEMM 128x128, BK=32, TRIPLE-buffered, counted vmcnt, 1 barrier/step ----------
// LDS = 48 KB. Tile s+2 stages into buf (s+2)%3 == (s-1)%3, whose ds_reads all
// completed (they feed the pre-barrier MFMAs via compiler lgkmcnt waits) before
// any wave passed THIS barrier -> no WAR hazard, no second barrier. WAITV(4):
// tile s resident, tile s+1's 4 loads stay in flight across the barrier.
// NO XCD swizzle (measured: chunked swizzle at gx=32 inflates FETCH 41->97 MB).
template <int EPI, typename OutT>
__global__ __launch_bounds__(256) void gemm_k(const short* __restrict__ A,
                                              const short* __restrict__ Bt,
                                              const float* __restrict__ bias,
                                              const float* __restrict__ resid,
                                              OutT* __restrict__ out,
                                              int M, int N, int K) {
    __shared__ __align__(16) short sA[3][128 * 32];
    __shared__ __align__(16) short sB[3][128 * 32];
    const int tid = threadIdx.x;
    const int lane = tid & 63, wave = tid >> 6;
    const int wr = (wave >> 1) * 64, wc = (wave & 1) * 64;
    const int lrow = lane & 15, quad = lane >> 4;
    const int bm = blockIdx.y * 128, bn = blockIdx.x * 128;
    const short* Ap = A + (long)(bm + (tid >> 2)) * K + (tid & 3) * 8;
    const short* Bp = Bt + (long)(bn + (tid >> 2)) * K + (tid & 3) * 8;
    const long rowstep = (long)64 * K;

    auto stage = [&](int q, int k0) {
        gl2lds16(Ap + k0,           sA[q] + tid * 8);
        gl2lds16(Ap + rowstep + k0, sA[q] + 2048 + tid * 8);
        gl2lds16(Bp + k0,           sB[q] + tid * 8);
        gl2lds16(Bp + rowstep + k0, sB[q] + 2048 + tid * 8);
    };

    f32x4 acc[4][4] = {};
    const int S = K >> 5;
    stage(0, 0);
    stage(1, 32);
    int cur = 0, nx2 = 2;
    for (int s = 0; s < S; ++s) {
        if (s + 1 < S) { WAITV(4); } else { WAITV(0); }   // tile s resident
        block_sync();
        if (s + 2 < S) stage(nx2, (s + 2) << 5);          // writes buf (s-1)%3: safe
        const short* pA = sA[cur];
        const short* pB = sB[cur];
        s8x af[4], bfr[4];
#pragma unroll
        for (int i = 0; i < 4; ++i) af[i]  = *(const s8x*)(pA + (wr + i*16 + lrow) * 32 + quad * 8);
#pragma unroll
        for (int j = 0; j < 4; ++j) bfr[j] = *(const s8x*)(pB + (wc + j*16 + lrow) * 32 + quad * 8);
#pragma unroll
        for (int i = 0; i < 4; ++i)
#pragma unroll
            for (int j = 0; j < 4; ++j)
                acc[i][j] = __builtin_amdgcn_mfma_f32_16x16x32_bf16(af[i], bfr[j], acc[i][j], 0, 0, 0);
        cur = (cur == 2) ? 0 : cur + 1;
        nx2 = (nx2 == 2) ? 0 : nx2 + 1;
    }
#pragma unroll
    for (int i = 0; i < 4; ++i) {
#pragma unroll
        for (int j = 0; j < 4; ++j) {
#pragma unroll
            for (int r = 0; r < 4; ++r) {
                const int row = bm + wr + i*16 + quad*4 + r;   // C/D: row = quad*4 + reg
                const int col = bn + wc + j*16 + lrow;         // C/D: col = lane&15
                epi_store<EPI>(out, resid, (long)row * N + col, acc[i][j][r] + bias[col]);
            }
        }
    }
}

// ---------- GEMM 128x64, BK=64 (2x32 panels), double-buffered, XCD-swizzled ----------
// Round-9-verified best config for the skinny-N GEMMs (proj, mlp): 54.7 us mlp.
// All occupancy levers (BK=32 triple, 64x64 tile, split-K atomics, 72KB triple)
// measured WORSE or neutral — this is the local optimum for this structure.
template <int EPI, typename OutT>
__global__ __launch_bounds__(256) void gemm128x64_k(const short* __restrict__ A,
                                                    const short* __restrict__ Bt,
                                                    const float* __restrict__ bias,
                                                    const float* __restrict__ resid,
                                                    OutT* __restrict__ out,
                                                    int M, int N, int K) {
    __shared__ __align__(16) short sA[2][2][128 * 32];
    __shared__ __align__(16) short sB[2][2][64 * 32];
    const int tid = threadIdx.x;
    const int lane = tid & 63, wave = tid >> 6;
    const int wr = (wave >> 1) * 64, wc = (wave & 1) * 32;
    const int lrow = lane & 15, quad = lane >> 4;
    // XCD-chunked bijective swizzle (nwg = 512, %8 == 0)
    const int gx = gridDim.x;
    const int nwg = gx * gridDim.y;
    const int bid = blockIdx.y * gx + blockIdx.x;
    const int swz = (bid & 7) * (nwg >> 3) + (bid >> 3);
    const int bm = (swz / gx) * 128, bn = (swz % gx) * 64;
    const short* Ap = A + (long)(bm + (tid >> 2)) * K + (tid & 3) * 8;
    const short* Bp = Bt + (long)(bn + (tid >> 2)) * K + (tid & 3) * 8;
    const long rowstep = (long)64 * K;

    auto stage = [&](int p, int k0) {
#pragma unroll
        for (int hp = 0; hp < 2; ++hp) {
            gl2lds16(Ap + k0 + hp * 32,           sA[p][hp] + tid * 8);
            gl2lds16(Ap + rowstep + k0 + hp * 32, sA[p][hp] + 2048 + tid * 8);
            gl2lds16(Bp + k0 + hp * 32,           sB[p][hp] + tid * 8);
        }
    };

    f32x4 acc[4][2] = {};
    stage(0, 0);
    const int S = K >> 6;
    for (int s = 0; s < S; ++s) {
        const int p = s & 1;
        __syncthreads();
        if (s + 1 < S) stage(p ^ 1, (s + 1) << 6);
#pragma unroll
        for (int hp = 0; hp < 2; ++hp) {
            s8x af[4], bfr[2];
#pragma unroll
            for (int i = 0; i < 4; ++i) af[i]  = *(const s8x*)(sA[p][hp] + (wr + i*16 + lrow) * 32 + quad * 8);
#pragma unroll
            for (int j = 0; j < 2; ++j) bfr[j] = *(const s8x*)(sB[p][hp] + (wc + j*16 + lrow) * 32 + quad * 8);
#pragma unroll
            for (int i = 0; i < 4; ++i)
#pragma unroll
                for (int j = 0; j < 2; ++j)
                    acc[i][j] = __builtin_amdgcn_mfma_f32_16x16x32_bf16(af[i], bfr[j], acc[i][j], 0, 0, 0);
        }
    }
#pragma unroll
    for (int i = 0; i < 4; ++i) {
#pragma unroll
        for (int j = 0; j < 2; ++j) {
#pragma unroll
            for (int r = 0; r < 4; ++r) {
                const int row = bm + wr + i*16 + quad*4 + r;
                const int col = bn + wc + j*16 + lrow;
                epi_store<EPI>(out, resid, (long)row * N + col, acc[i][j][r] + bias[col]);
            }
        }
    }
}

// ---------- attention common constants ----------
#define ATT_CS (0.125f * 1.4426950408889634f)  /* log2(e)/sqrt(64) */
#define ATT_C0 (14.426950408889634f)           /* 10*log2(e) fixed shift */

// hw transpose read: lane l receives column (l&15), rows j=0..3 of the [4][16]
// bf16 tile in the 128B window (l>>4); vaddr = base + lane*8B, offset literal.
#define TR16(dst, off) \
    asm volatile("ds_read_b64_tr_b16 %0, %1 offset:" off : "=v"(dst) : "v"(tva))

// ---------- paired-tile causal flash attention: B=2,H=16,T=2048,hs=64 ----------
// Pairs (bx, 31-bx): every block exactly 33 tile-iterations. Swapped QK^T
// (mfma(K,Q)) -> in-register softmax/l/pack + permlane rebuild of PV A-frag.
// V staged by direct global_load_lds DMA into tr_b16-compatible subtiled layout;
// PV B-frags via ds_read_b64_tr_b16 (shared by both q-tiles). Triple-buffered
// K/V (48 KB LDS) with counted vmcnt: next tile's loads fly across the barrier.
__global__ __launch_bounds__(256) void attn_k(const short* __restrict__ qkv,
                                              short* __restrict__ y) {
    const int bx = blockIdx.x;                 // 0..15
    const int b = blockIdx.y >> 4, h = blockIdx.y & 15;
    const int qtA = bx, qtB = 31 - bx;
    const int tid = threadIdx.x, lane = tid & 63, wave = tid >> 6;
    const int lrow = lane & 15, quad = lane >> 4;
    const long base = (long)b * 2048 * 3072;

    __shared__ __align__(16) short sK[3][64 * 64];
    __shared__ __align__(16) short sV[3][4096];

    s8x qfA0, qfA1, qfB0, qfB1;
    {
        const short* qpA = qkv + base + (long)(qtA * 64 + wave * 16 + lrow) * 3072 + h * 64 + quad * 8;
        qfA0 = *(const s8x*)qpA; qfA1 = *(const s8x*)(qpA + 32);
        const short* qpB = qkv + base + (long)(qtB * 64 + wave * 16 + lrow) * 3072 + h * 64 + quad * 8;
        qfB0 = *(const s8x*)qpB; qfB1 = *(const s8x*)(qpB + 32);
    }
    f32x4 oA[4], oB[4];
    float lA = 0.f, lB = 0.f;
#pragma unroll
    for (int d = 0; d < 4; ++d) { oA[d] = f32x4{0.f,0.f,0.f,0.f}; oB[d] = f32x4{0.f,0.f,0.f,0.f}; }

    // K staging (XOR-swizzled rows)
    const int srow = tid >> 3, sg = tid & 7;
    const int sw0 = ((srow & 7) ^ (srow >> 3)) & 7;
    const int sw1 = (((srow + 32) & 7) ^ ((srow + 32) >> 3)) & 7;
    const short* kbase = qkv + base + 1024 + h * 64;
    auto issueK = [&](int q, int k0) {
        gl2lds16(kbase + (long)(k0 + srow) * 3072      + (sg ^ sw0) * 8, sK[q] + tid * 8);
        gl2lds16(kbase + (long)(k0 + srow + 32) * 3072 + (sg ^ sw1) * 8, sK[q] + 2048 + tid * 8);
    };

    // V staging: pre-swizzled global source -> linear LDS (subtiled-for-tr layout)
    const int vslot   = (tid >> 3) & 7;
    const int vkbl    = 2 * (vslot & 3) + (vslot >> 2);
    const int vklocal = vkbl * 4 + ((tid >> 1) & 3);
    const short* vsrc = qkv + base + 2048 + h * 64
                      + (long)vklocal * 3072 + wave * 16 + 8 * (tid & 1);
    auto issueV = [&](int q, int k0) {
        gl2lds16(vsrc + (long)k0 * 3072,        sV[q] + tid * 8);        // ks=0 half
        gl2lds16(vsrc + (long)(k0 + 32) * 3072, sV[q] + 2048 + tid * 8); // ks=1 half
    };
    const unsigned trb = (unsigned)(unsigned long long)(&sV[0][0]) + (unsigned)lane * 8u;

    // swapped QK^T: st col = q (lane&15), row = key-local (quad*4+r)
    auto tile_step = [&](const s8x& qf0, const s8x& qf1, const s8x* kf0, const s8x* kf1,
                         const s8x (*vfr)[4], f32x4* o, float& lsum, int qt, int kt, int k0) {
        f32x4 s[4];
#pragma unroll
        for (int ct = 0; ct < 4; ++ct) {
            f32x4 t = f32x4{0.f, 0.f, 0.f, 0.f};
            t = __builtin_amdgcn_mfma_f32_16x16x32_bf16(kf0[ct], qf0, t, 0, 0, 0);
            t = __builtin_amdgcn_mfma_f32_16x16x32_bf16(kf1[ct], qf1, t, 0, 0, 0);
            s[ct] = t;
        }
        const int qrow = qt * 64 + wave * 16 + lrow;   // this lane's q
        float pv[4][4];
        if (kt == qt) {           // diagonal tile masking (uniform branch)
#pragma unroll
            for (int ct = 0; ct < 4; ++ct)
#pragma unroll
                for (int r = 0; r < 4; ++r) {
                    const int key = k0 + ct * 16 + quad * 4 + r;
                    const float pp = exp2f(fmaf(s[ct][r], ATT_CS, -ATT_C0));
                    const float pt = __uint_as_float(__float_as_uint(pp) & 0xFFFF0000u);
                    pv[ct][r] = (key > qrow) ? 0.f : pt;
                }
        } else {
#pragma unroll
            for (int ct = 0; ct < 4; ++ct)
#pragma unroll
                for (int r = 0; r < 4; ++r) {
                    const float pp = exp2f(fmaf(s[ct][r], ATT_CS, -ATT_C0));
                    pv[ct][r] = __uint_as_float(__float_as_uint(pp) & 0xFFFF0000u);
                }
        }
#pragma unroll
        for (int ct = 0; ct < 4; ++ct)
            lsum += (pv[ct][0] + pv[ct][1]) + (pv[ct][2] + pv[ct][3]);

        // pack P -> bf16 pairs: w2[ct][p] = keys {ct*16+4*quad+2p, +1} for q=lrow
        unsigned int w2[4][2];
#pragma unroll
        for (int ct = 0; ct < 4; ++ct)
#pragma unroll
            for (int p2 = 0; p2 < 2; ++p2)
                w2[ct][p2] = __builtin_amdgcn_perm(__float_as_uint(pv[ct][2 * p2 + 1]),
                                                   __float_as_uint(pv[ct][2 * p2]), 0x07060302u);
        // PV A-frag (lane needs P[q=lane&15][k=quad*8+e], e=0..7) via lane swaps
        s8x pa[2];
#pragma unroll
        for (int ks = 0; ks < 2; ++ks) {
            auto rAC = __builtin_amdgcn_permlane32_swap((int)w2[2 * ks][0], (int)w2[2 * ks + 1][0], false, false);
            auto rBD = __builtin_amdgcn_permlane32_swap((int)w2[2 * ks][1], (int)w2[2 * ks + 1][1], false, false);
            auto mAC = __builtin_amdgcn_permlane16_swap(rAC[0], rAC[1], false, false);
            auto mBD = __builtin_amdgcn_permlane16_swap(rBD[0], rBD[1], false, false);
            int4 f;
            f.x = mAC[0]; f.y = mBD[0]; f.z = mAC[1]; f.w = mBD[1];
            pa[ks] = *(const s8x*)&f;
        }
#pragma unroll
        for (int ks = 0; ks < 2; ++ks)
#pragma unroll
            for (int dt = 0; dt < 4; ++dt)
                o[dt] = __builtin_amdgcn_mfma_f32_16x16x32_bf16(pa[ks], vfr[ks][dt], o[dt], 0, 0, 0);
    };

    issueK(0, 0);   issueV(0, 0);
    issueK(1, 64);  issueV(1, 64);   // qtB >= 16: tile 1 always exists
    int cur = 0, nx2 = 2;
    for (int kt = 0; kt <= qtB; ++kt) {
        const int k0 = kt * 64;
        if (kt < qtB) { WAITV(4); } else { WAITV(0); }   // tile kt resident
        block_sync();
        if (kt + 2 <= qtB) { issueK(nx2, k0 + 128); issueV(nx2, k0 + 128); }

        // K fragments (compiler-managed LDS reads)
        s8x kf0[4], kf1[4];
#pragma unroll
        for (int ct = 0; ct < 4; ++ct) {
            const int row = ct * 16 + lrow;
            const int swr = ((row & 7) ^ (row >> 3)) & 7;
            kf0[ct] = *(const s8x*)(sK[cur] + row * 64 + ((quad ^ swr) * 8));
            kf1[ct] = *(const s8x*)(sK[cur] + row * 64 + (((4 + quad) ^ swr) * 8));
        }

        // V fragments via hw transpose reads (shared by both q-tiles)
        const unsigned tva = trb + (unsigned)(cur << 13);
        i32x2 tr[16];
        TR16(tr[0],  "0");    TR16(tr[1],  "512");
        TR16(tr[2],  "1024"); TR16(tr[3],  "1536");
        TR16(tr[4],  "2048"); TR16(tr[5],  "2560");
        TR16(tr[6],  "3072"); TR16(tr[7],  "3584");
        TR16(tr[8],  "4096"); TR16(tr[9],  "4608");
        TR16(tr[10], "5120"); TR16(tr[11], "5632");
        TR16(tr[12], "6144"); TR16(tr[13], "6656");
        TR16(tr[14], "7168"); TR16(tr[15], "7680");
        asm volatile("s_waitcnt lgkmcnt(0)" ::: "memory");
        __builtin_amdgcn_sched_barrier(0);       // rule #18: pin MFMAs after the wait
        s8x vfr[2][4];
#pragma unroll
        for (int ks = 0; ks < 2; ++ks)
#pragma unroll
            for (int dt = 0; dt < 4; ++dt) {
                const int i2 = ks * 8 + dt * 2;
                int4 f;
                f.x = tr[i2][0]; f.y = tr[i2][1];
                f.z = tr[i2 + 1][0]; f.w = tr[i2 + 1][1];
                vfr[ks][dt] = *(const s8x*)&f;
            }

        if (kt <= qtA) tile_step(qfA0, qfA1, kf0, kf1, vfr, oA, lA, qtA, kt, k0);
        tile_step(qfB0, qfB1, kf0, kf1, vfr, oB, lB, qtB, kt, k0);

        cur = (cur == 2) ? 0 : cur + 1;
        nx2 = (nx2 == 2) ? 0 : nx2 + 1;
    }

    // l lives per-lane at q=lane&15: reduce across quads, redistribute to C rows
    lA += __shfl_xor(lA, 16, 64); lA += __shfl_xor(lA, 32, 64);
    lB += __shfl_xor(lB, 16, 64); lB += __shfl_xor(lB, 32, 64);
    float rA[4], rB[4];
#pragma unroll
    for (int r = 0; r < 4; ++r) {
        rA[r] = 1.0f / __shfl(lA, quad * 4 + r, 64);
        rB[r] = 1.0f / __shfl(lB, quad * 4 + r, 64);
    }
#pragma unroll
    for (int dt = 0; dt < 4; ++dt) {
#pragma unroll
        for (int r = 0; r < 4; ++r) {
            const int qA = qtA * 64 + wave * 16 + quad * 4 + r;
            const int qB = qtB * 64 + wave * 16 + quad * 4 + r;
            y[((long)b * 2048 + qA) * 1024 + h * 64 + dt * 16 + lrow] = f2bf(oA[dt][r] * rA[r]);
            y[((long)b * 2048 + qB) * 1024 + h * 64 + dt * 16 + lrow] = f2bf(oB[dt][r] * rB[r]);
        }
    }
}

// ---------- launch ----------
extern "C" void kernel_launch(void* const* d_in, const int* in_sizes, int n_in,
                              void* d_out, int out_size, void* d_ws, size_t ws_size,
                              hipStream_t stream) {
    const float* x      = (const float*)d_in[0];
    const float* ln1_w  = (const float*)d_in[1];
    const float* ln1_b  = (const float*)d_in[2];
    const float* attn_w = (const float*)d_in[3];
    const float* attn_b = (const float*)d_in[4];
    const float* proj_w = (const float*)d_in[5];
    const float* proj_b = (const float*)d_in[6];
    const float* ln2_w  = (const float*)d_in[7];
    const float* ln2_b  = (const float*)d_in[8];
    const float* fc_w   = (const float*)d_in[9];
    const float* fc_b   = (const float*)d_in[10];
    const float* mlp_w  = (const float*)d_in[11];
    const float* mlp_b  = (const float*)d_in[12];

    char* ws = (char*)d_ws;
    short* attn_wt = (short*)(ws + 0);           // [3072,1024] bf16
    short* proj_wt = (short*)(ws + 6291456L);    // [1024,1024] bf16
    short* fc_wt   = (short*)(ws + 8388608L);    // [4096,1024] bf16
    short* mlp_wt  = (short*)(ws + 16777216L);   // [1024,4096] bf16
    short* slotA   = (short*)(ws + 25165824L);   // xln / y / h  [4096,1024] bf16
    short* slotB   = (short*)(ws + 33554432L);   // qkv [4096,3072] / hh [4096,4096] bf16
    // total ws use: 67,108,864 bytes (64 MB)

    short* xln  = slotA;
    short* yb   = slotA;
    short* hb   = slotA;
    short* qkvb = slotB;
    short* hh   = slotB;
    float* x1   = (float*)d_out;   // f32 residual stream lives in d_out
    float* outp = (float*)d_out;

    // transposes + LN1 fused (independent inputs)
    pre_k<<<4096, 256, 0, stream>>>(attn_w, proj_w, fc_w, mlp_w,
                                    attn_wt, proj_wt, fc_wt, mlp_wt,
                                    x, ln1_w, ln1_b, xln);

    gemm_k<0, short><<<dim3(24, 32), 256, 0, stream>>>(xln, attn_wt, attn_b, nullptr, qkvb, 4096, 3072, 1024);
    attn_k<<<dim3(16, 32), 256, 0, stream>>>(qkvb, yb);
    gemm128x64_k<2, float><<<dim3(16, 32), 256, 0, stream>>>(yb, proj_wt, proj_b, x, x1, 4096, 1024, 1024);
    ln_k<<<1024, 256, 0, stream>>>(x1, ln2_w, ln2_b, hb);
    gemm_k<1, short><<<dim3(32, 32), 256, 0, stream>>>(hb, fc_wt, fc_b, nullptr, hh, 4096, 4096, 1024);
    gemm128x64_k<3, float><<<dim3(16, 32), 256, 0, stream>>>(hh, mlp_wt, mlp_b, x1, outp, 4096, 1024, 4096);
}

// Round 15
// 324.558 us; speedup vs baseline: 1.0462x; 1.0016x over previous
//
#include <hip/hip_runtime.h>
#include <math.h>

// ---------- types / helpers ----------
typedef short s8x __attribute__((ext_vector_type(8)));    // 8 bf16 (4 VGPRs) MFMA A/B frag
typedef float f32x4 __attribute__((ext_vector_type(4)));  // 16x16 MFMA C/D frag
typedef int   i32x2 __attribute__((ext_vector_type(2)));  // 64-bit tr-read result

__device__ __forceinline__ float bf2f(short u) {
    return __uint_as_float(((unsigned int)(unsigned short)u) << 16);
}
__device__ __forceinline__ short f2bf(float f) {
    unsigned int x = __float_as_uint(f);
    unsigned int r = (x + 0x7FFFu + ((x >> 16) & 1u)) >> 16; // RNE
    return (short)(unsigned short)r;
}

// async global->LDS, 16B per lane. LDS dest must be wave-uniform base + lane*16.
__device__ __forceinline__ void gl2lds16(const short* g, const short* l) {
    __builtin_amdgcn_global_load_lds(
        (const __attribute__((address_space(1))) void*)(unsigned long long)g,
        (__attribute__((address_space(3))) void*)(unsigned int)(unsigned long long)l,
        16, 0, 0);
}

// raw barrier with compiler memory fences (no vmcnt(0) drain, unlike __syncthreads)
__device__ __forceinline__ void block_sync() {
    asm volatile("" ::: "memory");
    __builtin_amdgcn_s_barrier();
    asm volatile("" ::: "memory");
}
#define WAITV(n) asm volatile("s_waitcnt vmcnt(" #n ")" ::: "memory")

// pack two f32 -> one dword of 2 bf16 (RNE): lo = bf16(a), hi = bf16(b)
__device__ __forceinline__ unsigned cvtpk_bf16(float a, float b) {
    unsigned r;
    asm("v_cvt_pk_bf16_f32 %0, %1, %2" : "=v"(r) : "v"(a), "v"(b));
    return r;
}

// ---------- wave-per-row LayerNorm core: f32 in -> bf16 out, C=1024 ----------
__device__ __forceinline__ void ln_row(const float* __restrict__ xin,
                                       const float* __restrict__ w,
                                       const float* __restrict__ bb,
                                       short* __restrict__ out, int row, int lane) {
    const float4* xr = (const float4*)(xin + (long)row * 1024);
    float4 v[4];
    float s1 = 0.f, s2 = 0.f;
#pragma unroll
    for (int i = 0; i < 4; ++i) {
        v[i] = xr[lane + i * 64];
        s1 += v[i].x + v[i].y + v[i].z + v[i].w;
        s2 += v[i].x*v[i].x + v[i].y*v[i].y + v[i].z*v[i].z + v[i].w*v[i].w;
    }
#pragma unroll
    for (int off = 32; off > 0; off >>= 1) {
        s1 += __shfl_xor(s1, off, 64);
        s2 += __shfl_xor(s2, off, 64);
    }
    const float mu = s1 * (1.0f / 1024.0f);
    float var = s2 * (1.0f / 1024.0f) - mu * mu;
    var = fmaxf(var, 0.0f);
    const float rs = rsqrtf(var + 1e-5f);
    short4* orow = (short4*)(out + (long)row * 1024);
#pragma unroll
    for (int i = 0; i < 4; ++i) {
        const int ci = (lane + i * 64) * 4;
        const float4 wv = *(const float4*)(w + ci);
        const float4 bv = *(const float4*)(bb + ci);
        short4 o;
        o.x = f2bf((v[i].x - mu) * rs * wv.x + bv.x);
        o.y = f2bf((v[i].y - mu) * rs * wv.y + bv.y);
        o.z = f2bf((v[i].z - mu) * rs * wv.z + bv.z);
        o.w = f2bf((v[i].w - mu) * rs * wv.w + bv.w);
        orow[lane + i * 64] = o;
    }
}

__global__ __launch_bounds__(256) void ln_k(const float* __restrict__ xin,
                                            const float* __restrict__ w,
                                            const float* __restrict__ bb,
                                            short* __restrict__ out) {
    ln_row(xin, w, bb, out, blockIdx.x * 4 + (threadIdx.x >> 6), threadIdx.x & 63);
}

// ---------- fused: 4 weight transposes (f32 [K][N] -> bf16 [N][K]) + LN1 ----------
// 64x64 tiles, float4 reads (1 KB/wave-instr) + short4 writes (512 B/wave-instr);
// LDS [64][65] pad keeps both phases <=2-way bank aliasing (free).
__global__ __launch_bounds__(256) void pre_k(
        const float* __restrict__ w0, const float* __restrict__ w1,
        const float* __restrict__ w2, const float* __restrict__ w3,
        short* __restrict__ o0, short* __restrict__ o1,
        short* __restrict__ o2, short* __restrict__ o3,
        const float* __restrict__ x, const float* __restrict__ ln1w,
        const float* __restrict__ ln1b, short* __restrict__ xln) {
    int bid = blockIdx.x;
    if (bid >= 3072) {   // LN1: 1024 blocks, 4 rows each (wave per row)
        ln_row(x, ln1w, ln1b, xln, (bid - 3072) * 4 + (threadIdx.x >> 6), threadIdx.x & 63);
        return;
    }
    const float* in; short* out; int K, N, nx;
    if (bid < 768)       { in = w0; out = o0; K = 1024; N = 3072; nx = 48; }
    else if (bid < 1024) { bid -= 768;  in = w1; out = o1; K = 1024; N = 1024; nx = 16; }
    else if (bid < 2048) { bid -= 1024; in = w2; out = o2; K = 1024; N = 4096; nx = 64; }
    else                 { bid -= 2048; in = w3; out = o3; K = 4096; N = 1024; nx = 16; }
    const int n0 = (bid % nx) * 64, k0 = (bid / nx) * 64;
    __shared__ float tile[64][65];
    const int tx = threadIdx.x & 15, ty = threadIdx.x >> 4;  // ty 0..15
#pragma unroll
    for (int p = 0; p < 4; ++p) {
        const int k = p * 16 + ty;
        const float4 v = *(const float4*)(in + (long)(k0 + k) * N + n0 + tx * 4);
        tile[k][tx * 4 + 0] = v.x;
        tile[k][tx * 4 + 1] = v.y;
        tile[k][tx * 4 + 2] = v.z;
        tile[k][tx * 4 + 3] = v.w;
    }
    __syncthreads();
#pragma unroll
    for (int p = 0; p < 4; ++p) {
        const int n = p * 16 + ty;
        short4 o;
        o.x = f2bf(tile[tx * 4 + 0][n]);
        o.y = f2bf(tile[tx * 4 + 1][n]);
        o.z = f2bf(tile[tx * 4 + 2][n]);
        o.w = f2bf(tile[tx * 4 + 3][n]);
        *(short4*)(out + (long)(n0 + n) * K + k0 + tx * 4) = o;
    }
}

// ---------- GEMM epilogue ----------
// EPI 1 GELU: tanh-form (sigmoid identity), |delta vs exact erf| < 3e-3 << bf16 tol.
template <int EPI, typename OutT>
__device__ __forceinline__ void epi_store(OutT* out, const float* resid, long oidx, float v) {
    if constexpr (EPI == 0) {
        out[oidx] = f2bf(v);
    } else if constexpr (EPI == 1) {
        const float u = v * (0.79788456080f + 0.03567740814f * v * v);
        v = v / (1.0f + __expf(-2.0f * u));
        out[oidx] = f2bf(v);
    } else {
        v += resid[oidx];
        out[oidx] = v;   // f32 store
    }
}

// ---------- GEMM 128x128, BK=32, TRIPLE-buffered, counted vmcnt, 1 barrier/step ----------
// LDS = 48 KB. Tile s+2 stages into buf (s+2)%3 == (s-1)%3, whose ds_reads all
// completed before any wave passed THIS barrier -> no WAR hazard, no second
// barrier. WAITV(4): tile s resident, tile s+1's loads stay in flight.
// NO XCD swizzle (measured: chunked swizzle at gx=32 inflates FETCH 41->97 MB).
template <int EPI, typename OutT>
__global__ __launch_bounds__(256) void gemm_k(const short* __restrict__ A,
                                              const short* __restrict__ Bt,
                                              const float* __restrict__ bias,
                                              const float* __restrict__ resid,
                                              OutT* __restrict__ out,
                                              int M, int N, int K) {
    __shared__ __align__(16) short sA[3][128 * 32];
    __shared__ __align__(16) short sB[3][128 * 32];
    const int tid = threadIdx.x;
    const int lane = tid & 63, wave = tid >> 6;
    const int wr = (wave >> 1) * 64, wc = (wave & 1) * 64;
    const int lrow = lane & 15, quad = lane >> 4;
    const int bm = blockIdx.y * 128, bn = blockIdx.x * 128;
    const short* Ap = A + (long)(bm + (tid >> 2)) * K + (tid & 3) * 8;
    const short* Bp = Bt + (long)(bn + (tid >> 2)) * K + (tid & 3) * 8;
    const long rowstep = (long)64 * K;

    auto stage = [&](int q, int k0) {
        gl2lds16(Ap + k0,           sA[q] + tid * 8);
        gl2lds16(Ap + rowstep + k0, sA[q] + 2048 + tid * 8);
        gl2lds16(Bp + k0,           sB[q] + tid * 8);
        gl2lds16(Bp + rowstep + k0, sB[q] + 2048 + tid * 8);
    };

    f32x4 acc[4][4] = {};
    const int S = K >> 5;
    stage(0, 0);
    stage(1, 32);
    int cur = 0, nx2 = 2;
    for (int s = 0; s < S; ++s) {
        if (s + 1 < S) { WAITV(4); } else { WAITV(0); }   // tile s resident
        block_sync();
        if (s + 2 < S) stage(nx2, (s + 2) << 5);          // writes buf (s-1)%3: safe
        const short* pA = sA[cur];
        const short* pB = sB[cur];
        s8x af[4], bfr[4];
#pragma unroll
        for (int i = 0; i < 4; ++i) af[i]  = *(const s8x*)(pA + (wr + i*16 + lrow) * 32 + quad * 8);
#pragma unroll
        for (int j = 0; j < 4; ++j) bfr[j] = *(const s8x*)(pB + (wc + j*16 + lrow) * 32 + quad * 8);
#pragma unroll
        for (int i = 0; i < 4; ++i)
#pragma unroll
            for (int j = 0; j < 4; ++j)
                acc[i][j] = __builtin_amdgcn_mfma_f32_16x16x32_bf16(af[i], bfr[j], acc[i][j], 0, 0, 0);
        cur = (cur == 2) ? 0 : cur + 1;
        nx2 = (nx2 == 2) ? 0 : nx2 + 1;
    }
#pragma unroll
    for (int i = 0; i < 4; ++i) {
#pragma unroll
        for (int j = 0; j < 4; ++j) {
#pragma unroll
            for (int r = 0; r < 4; ++r) {
                const int row = bm + wr + i*16 + quad*4 + r;   // C/D: row = quad*4 + reg
                const int col = bn + wc + j*16 + lrow;         // C/D: col = lane&15
                epi_store<EPI>(out, resid, (long)row * N + col, acc[i][j][r] + bias[col]);
            }
        }
    }
}

// ---------- GEMM 128x64, BK=64 (2x32 panels), double-buffered, XCD-swizzled ----------
// Round-9-verified best config for the skinny-N GEMMs (proj, mlp): 54.7 us mlp.
template <int EPI, typename OutT>
__global__ __launch_bounds__(256) void gemm128x64_k(const short* __restrict__ A,
                                                    const short* __restrict__ Bt,
                                                    const float* __restrict__ bias,
                                                    const float* __restrict__ resid,
                                                    OutT* __restrict__ out,
                                                    int M, int N, int K) {
    __shared__ __align__(16) short sA[2][2][128 * 32];
    __shared__ __align__(16) short sB[2][2][64 * 32];
    const int tid = threadIdx.x;
    const int lane = tid & 63, wave = tid >> 6;
    const int wr = (wave >> 1) * 64, wc = (wave & 1) * 32;
    const int lrow = lane & 15, quad = lane >> 4;
    // XCD-chunked bijective swizzle (nwg = 512, %8 == 0)
    const int gx = gridDim.x;
    const int nwg = gx * gridDim.y;
    const int bid = blockIdx.y * gx + blockIdx.x;
    const int swz = (bid & 7) * (nwg >> 3) + (bid >> 3);
    const int bm = (swz / gx) * 128, bn = (swz % gx) * 64;
    const short* Ap = A + (long)(bm + (tid >> 2)) * K + (tid & 3) * 8;
    const short* Bp = Bt + (long)(bn + (tid >> 2)) * K + (tid & 3) * 8;
    const long rowstep = (long)64 * K;

    auto stage = [&](int p, int k0) {
#pragma unroll
        for (int hp = 0; hp < 2; ++hp) {
            gl2lds16(Ap + k0 + hp * 32,           sA[p][hp] + tid * 8);
            gl2lds16(Ap + rowstep + k0 + hp * 32, sA[p][hp] + 2048 + tid * 8);
            gl2lds16(Bp + k0 + hp * 32,           sB[p][hp] + tid * 8);
        }
    };

    f32x4 acc[4][2] = {};
    stage(0, 0);
    const int S = K >> 6;
    for (int s = 0; s < S; ++s) {
        const int p = s & 1;
        __syncthreads();
        if (s + 1 < S) stage(p ^ 1, (s + 1) << 6);
#pragma unroll
        for (int hp = 0; hp < 2; ++hp) {
            s8x af[4], bfr[2];
#pragma unroll
            for (int i = 0; i < 4; ++i) af[i]  = *(const s8x*)(sA[p][hp] + (wr + i*16 + lrow) * 32 + quad * 8);
#pragma unroll
            for (int j = 0; j < 2; ++j) bfr[j] = *(const s8x*)(sB[p][hp] + (wc + j*16 + lrow) * 32 + quad * 8);
#pragma unroll
            for (int i = 0; i < 4; ++i)
#pragma unroll
                for (int j = 0; j < 2; ++j)
                    acc[i][j] = __builtin_amdgcn_mfma_f32_16x16x32_bf16(af[i], bfr[j], acc[i][j], 0, 0, 0);
        }
    }
#pragma unroll
    for (int i = 0; i < 4; ++i) {
#pragma unroll
        for (int j = 0; j < 2; ++j) {
#pragma unroll
            for (int r = 0; r < 4; ++r) {
                const int row = bm + wr + i*16 + quad*4 + r;
                const int col = bn + wc + j*16 + lrow;
                epi_store<EPI>(out, resid, (long)row * N + col, acc[i][j][r] + bias[col]);
            }
        }
    }
}

// ---------- attention common constants ----------
#define ATT_CS (0.125f * 1.4426950408889634f)  /* log2(e)/sqrt(64) */
#define ATT_C0 (14.426950408889634f)           /* 10*log2(e) fixed shift */

// hw transpose read: lane l receives column (l&15), rows j=0..3 of the [4][16]
// bf16 tile in the 128B window (l>>4); vaddr = base + lane*8B, offset literal.
#define TR16(dst, off) \
    asm volatile("ds_read_b64_tr_b16 %0, %1 offset:" off : "=v"(dst) : "v"(tva))

// ---------- paired-tile causal flash attention: B=2,H=16,T=2048,hs=64 ----------
// Pairs (bx, 31-bx): every block exactly 33 tile-iterations. Swapped QK^T
// (mfma(K,Q)) -> in-register softmax. VALU-pipe diet (round-14 profile showed
// VALUBusy 55% / MfmaUtil 12%): P packing via v_cvt_pk_bf16_f32 (8 ops, RNE)
// instead of 16 AND + 8 v_perm; row-sum l via ones-MFMA on the pa fragments
// (idle MFMA pipe) instead of 15 VALU adds — and l lands directly in the C/D
// row layout (no epilogue shuffles). l = exact sum of the bf16 P used in PV.
__global__ __launch_bounds__(256) void attn_k(const short* __restrict__ qkv,
                                              short* __restrict__ y) {
    const int bx = blockIdx.x;                 // 0..15
    const int b = blockIdx.y >> 4, h = blockIdx.y & 15;
    const int qtA = bx, qtB = 31 - bx;
    const int tid = threadIdx.x, lane = tid & 63, wave = tid >> 6;
    const int lrow = lane & 15, quad = lane >> 4;
    const long base = (long)b * 2048 * 3072;

    __shared__ __align__(16) short sK[3][64 * 64];
    __shared__ __align__(16) short sV[3][4096];

    s8x qfA0, qfA1, qfB0, qfB1;
    {
        const short* qpA = qkv + base + (long)(qtA * 64 + wave * 16 + lrow) * 3072 + h * 64 + quad * 8;
        qfA0 = *(const s8x*)qpA; qfA1 = *(const s8x*)(qpA + 32);
        const short* qpB = qkv + base + (long)(qtB * 64 + wave * 16 + lrow) * 3072 + h * 64 + quad * 8;
        qfB0 = *(const s8x*)qpB; qfB1 = *(const s8x*)(qpB + 32);
    }
    f32x4 oA[4], oB[4], lA4 = {}, lB4 = {};
#pragma unroll
    for (int d = 0; d < 4; ++d) { oA[d] = f32x4{0.f,0.f,0.f,0.f}; oB[d] = f32x4{0.f,0.f,0.f,0.f}; }
    s8x ones;
#pragma unroll
    for (int j = 0; j < 8; ++j) ones[j] = (short)0x3F80;   // bf16 1.0

    // K staging (XOR-swizzled rows)
    const int srow = tid >> 3, sg = tid & 7;
    const int sw0 = ((srow & 7) ^ (srow >> 3)) & 7;
    const int sw1 = (((srow + 32) & 7) ^ ((srow + 32) >> 3)) & 7;
    const short* kbase = qkv + base + 1024 + h * 64;
    auto issueK = [&](int q, int k0) {
        gl2lds16(kbase + (long)(k0 + srow) * 3072      + (sg ^ sw0) * 8, sK[q] + tid * 8);
        gl2lds16(kbase + (long)(k0 + srow + 32) * 3072 + (sg ^ sw1) * 8, sK[q] + 2048 + tid * 8);
    };

    // V staging: pre-swizzled global source -> linear LDS (subtiled-for-tr layout)
    const int vslot   = (tid >> 3) & 7;
    const int vkbl    = 2 * (vslot & 3) + (vslot >> 2);
    const int vklocal = vkbl * 4 + ((tid >> 1) & 3);
    const short* vsrc = qkv + base + 2048 + h * 64
                      + (long)vklocal * 3072 + wave * 16 + 8 * (tid & 1);
    auto issueV = [&](int q, int k0) {
        gl2lds16(vsrc + (long)k0 * 3072,        sV[q] + tid * 8);        // ks=0 half
        gl2lds16(vsrc + (long)(k0 + 32) * 3072, sV[q] + 2048 + tid * 8); // ks=1 half
    };
    const unsigned trb = (unsigned)(unsigned long long)(&sV[0][0]) + (unsigned)lane * 8u;

    // swapped QK^T: st col = q (lane&15), row = key-local (quad*4+r)
    auto tile_step = [&](const s8x& qf0, const s8x& qf1, const s8x* kf0, const s8x* kf1,
                         const s8x (*vfr)[4], f32x4* o, f32x4& lacc, int qt, int kt, int k0) {
        f32x4 s[4];
#pragma unroll
        for (int ct = 0; ct < 4; ++ct) {
            f32x4 t = f32x4{0.f, 0.f, 0.f, 0.f};
            t = __builtin_amdgcn_mfma_f32_16x16x32_bf16(kf0[ct], qf0, t, 0, 0, 0);
            t = __builtin_amdgcn_mfma_f32_16x16x32_bf16(kf1[ct], qf1, t, 0, 0, 0);
            s[ct] = t;
        }
        const int qrow = qt * 64 + wave * 16 + lrow;   // this lane's q
        float pm[4][4];
        if (kt == qt) {           // diagonal tile masking (uniform branch)
#pragma unroll
            for (int ct = 0; ct < 4; ++ct)
#pragma unroll
                for (int r = 0; r < 4; ++r) {
                    const int key = k0 + ct * 16 + quad * 4 + r;
                    const float pp = exp2f(fmaf(s[ct][r], ATT_CS, -ATT_C0));
                    pm[ct][r] = (key > qrow) ? 0.f : pp;
                }
        } else {
#pragma unroll
            for (int ct = 0; ct < 4; ++ct)
#pragma unroll
                for (int r = 0; r < 4; ++r)
                    pm[ct][r] = exp2f(fmaf(s[ct][r], ATT_CS, -ATT_C0));
        }

        // pack P -> bf16 pairs (RNE): w2[ct][p] = keys {ct*16+4*quad+2p, +1}, q=lrow
        unsigned int w2[4][2];
#pragma unroll
        for (int ct = 0; ct < 4; ++ct)
#pragma unroll
            for (int p2 = 0; p2 < 2; ++p2)
                w2[ct][p2] = cvtpk_bf16(pm[ct][2 * p2], pm[ct][2 * p2 + 1]);
        // PV A-frag (lane needs P[q=lane&15][k=quad*8+e], e=0..7) via lane swaps
        s8x pa[2];
#pragma unroll
        for (int ks = 0; ks < 2; ++ks) {
            auto rAC = __builtin_amdgcn_permlane32_swap((int)w2[2 * ks][0], (int)w2[2 * ks + 1][0], false, false);
            auto rBD = __builtin_amdgcn_permlane32_swap((int)w2[2 * ks][1], (int)w2[2 * ks + 1][1], false, false);
            auto mAC = __builtin_amdgcn_permlane16_swap(rAC[0], rAC[1], false, false);
            auto mBD = __builtin_amdgcn_permlane16_swap(rBD[0], rBD[1], false, false);
            int4 f;
            f.x = mAC[0]; f.y = mBD[0]; f.z = mAC[1]; f.w = mBD[1];
            pa[ks] = *(const s8x*)&f;
        }
#pragma unroll
        for (int ks = 0; ks < 2; ++ks) {
            lacc = __builtin_amdgcn_mfma_f32_16x16x32_bf16(pa[ks], ones, lacc, 0, 0, 0);
#pragma unroll
            for (int dt = 0; dt < 4; ++dt)
                o[dt] = __builtin_amdgcn_mfma_f32_16x16x32_bf16(pa[ks], vfr[ks][dt], o[dt], 0, 0, 0);
        }
    };

    issueK(0, 0);   issueV(0, 0);
    issueK(1, 64);  issueV(1, 64);   // qtB >= 16: tile 1 always exists
    int cur = 0, nx2 = 2;
    for (int kt = 0; kt <= qtB; ++kt) {
        const int k0 = kt * 64;
        if (kt < qtB) { WAITV(4); } else { WAITV(0); }   // tile kt resident
        block_sync();
        if (kt + 2 <= qtB) { issueK(nx2, k0 + 128); issueV(nx2, k0 + 128); }

        // K fragments (compiler-managed LDS reads)
        s8x kf0[4], kf1[4];
#pragma unroll
        for (int ct = 0; ct < 4; ++ct) {
            const int row = ct * 16 + lrow;
            const int swr = ((row & 7) ^ (row >> 3)) & 7;
            kf0[ct] = *(const s8x*)(sK[cur] + row * 64 + ((quad ^ swr) * 8));
            kf1[ct] = *(const s8x*)(sK[cur] + row * 64 + (((4 + quad) ^ swr) * 8));
        }

        // V fragments via hw transpose reads (shared by both q-tiles)
        const unsigned tva = trb + (unsigned)(cur << 13);
        i32x2 tr[16];
        TR16(tr[0],  "0");    TR16(tr[1],  "512");
        TR16(tr[2],  "1024"); TR16(tr[3],  "1536");
        TR16(tr[4],  "2048"); TR16(tr[5],  "2560");
        TR16(tr[6],  "3072"); TR16(tr[7],  "3584");
        TR16(tr[8],  "4096"); TR16(tr[9],  "4608");
        TR16(tr[10], "5120"); TR16(tr[11], "5632");
        TR16(tr[12], "6144"); TR16(tr[13], "6656");
        TR16(tr[14], "7168"); TR16(tr[15], "7680");
        asm volatile("s_waitcnt lgkmcnt(0)" ::: "memory");
        __builtin_amdgcn_sched_barrier(0);       // rule #18: pin MFMAs after the wait
        s8x vfr[2][4];
#pragma unroll
        for (int ks = 0; ks < 2; ++ks)
#pragma unroll
            for (int dt = 0; dt < 4; ++dt) {
                const int i2 = ks * 8 + dt * 2;
                int4 f;
                f.x = tr[i2][0]; f.y = tr[i2][1];
                f.z = tr[i2 + 1][0]; f.w = tr[i2 + 1][1];
                vfr[ks][dt] = *(const s8x*)&f;
            }

        if (kt <= qtA) tile_step(qfA0, qfA1, kf0, kf1, vfr, oA, lA4, qtA, kt, k0);
        tile_step(qfB0, qfB1, kf0, kf1, vfr, oB, lB4, qtB, kt, k0);

        cur = (cur == 2) ? 0 : cur + 1;
        nx2 = (nx2 == 2) ? 0 : nx2 + 1;
    }

    // l via ones-MFMA already lives at row = quad*4 + r (matches O rows): no shuffles
    float rA[4], rB[4];
#pragma unroll
    for (int r = 0; r < 4; ++r) {
        rA[r] = 1.0f / lA4[r];
        rB[r] = 1.0f / lB4[r];
    }
#pragma unroll
    for (int dt = 0; dt < 4; ++dt) {
#pragma unroll
        for (int r = 0; r < 4; ++r) {
            const int qA = qtA * 64 + wave * 16 + quad * 4 + r;
            const int qB = qtB * 64 + wave * 16 + quad * 4 + r;
            y[((long)b * 2048 + qA) * 1024 + h * 64 + dt * 16 + lrow] = f2bf(oA[dt][r] * rA[r]);
            y[((long)b * 2048 + qB) * 1024 + h * 64 + dt * 16 + lrow] = f2bf(oB[dt][r] * rB[r]);
        }
    }
}

// ---------- launch ----------
extern "C" void kernel_launch(void* const* d_in, const int* in_sizes, int n_in,
                              void* d_out, int out_size, void* d_ws, size_t ws_size,
                              hipStream_t stream) {
    const float* x      = (const float*)d_in[0];
    const float* ln1_w  = (const float*)d_in[1];
    const float* ln1_b  = (const float*)d_in[2];
    const float* attn_w = (const float*)d_in[3];
    const float* attn_b = (const float*)d_in[4];
    const float* proj_w = (const float*)d_in[5];
    const float* proj_b = (const float*)d_in[6];
    const float* ln2_w  = (const float*)d_in[7];
    const float* ln2_b  = (const float*)d_in[8];
    const float* fc_w   = (const float*)d_in[9];
    const float* fc_b   = (const float*)d_in[10];
    const float* mlp_w  = (const float*)d_in[11];
    const float* mlp_b  = (const float*)d_in[12];

    char* ws = (char*)d_ws;
    short* attn_wt = (short*)(ws + 0);           // [3072,1024] bf16
    short* proj_wt = (short*)(ws + 6291456L);    // [1024,1024] bf16
    short* fc_wt   = (short*)(ws + 8388608L);    // [4096,1024] bf16
    short* mlp_wt  = (short*)(ws + 16777216L);   // [1024,4096] bf16
    short* slotA   = (short*)(ws + 25165824L);   // xln / y / h  [4096,1024] bf16
    short* slotB   = (short*)(ws + 33554432L);   // qkv [4096,3072] / hh [4096,4096] bf16
    // total ws use: 67,108,864 bytes (64 MB)

    short* xln  = slotA;
    short* yb   = slotA;
    short* hb   = slotA;
    short* qkvb = slotB;
    short* hh   = slotB;
    float* x1   = (float*)d_out;   // f32 residual stream lives in d_out
    float* outp = (float*)d_out;

    // transposes + LN1 fused (independent inputs)
    pre_k<<<4096, 256, 0, stream>>>(attn_w, proj_w, fc_w, mlp_w,
                                    attn_wt, proj_wt, fc_wt, mlp_wt,
                                    x, ln1_w, ln1_b, xln);

    gemm_k<0, short><<<dim3(24, 32), 256, 0, stream>>>(xln, attn_wt, attn_b, nullptr, qkvb, 4096, 3072, 1024);
    attn_k<<<dim3(16, 32), 256, 0, stream>>>(qkvb, yb);
    gemm128x64_k<2, float><<<dim3(16, 32), 256, 0, stream>>>(yb, proj_wt, proj_b, x, x1, 4096, 1024, 1024);
    ln_k<<<1024, 256, 0, stream>>>(x1, ln2_w, ln2_b, hb);
    gemm_k<1, short><<<dim3(32, 32), 256, 0, stream>>>(hb, fc_wt, fc_b, nullptr, hh, 4096, 4096, 1024);
    gemm128x64_k<3, float><<<dim3(16, 32), 256, 0, stream>>>(hh, mlp_wt, mlp_b, x1, outp, 4096, 1024, 4096);
}

// Round 16
// 318.444 us; speedup vs baseline: 1.0663x; 1.0192x over previous
//
#include <hip/hip_runtime.h>
#include <math.h>

// ---------- types / helpers ----------
typedef short s8x __attribute__((ext_vector_type(8)));    // 8 bf16 (4 VGPRs) MFMA A/B frag
typedef float f32x4 __attribute__((ext_vector_type(4)));  // 16x16 MFMA C/D frag
typedef int   i32x2 __attribute__((ext_vector_type(2)));  // 64-bit tr-read result

__device__ __forceinline__ float bf2f(short u) {
    return __uint_as_float(((unsigned int)(unsigned short)u) << 16);
}
__device__ __forceinline__ short f2bf(float f) {
    unsigned int x = __float_as_uint(f);
    unsigned int r = (x + 0x7FFFu + ((x >> 16) & 1u)) >> 16; // RNE
    return (short)(unsigned short)r;
}

// async global->LDS, 16B per lane. LDS dest must be wave-uniform base + lane*16.
__device__ __forceinline__ void gl2lds16(const short* g, const short* l) {
    __builtin_amdgcn_global_load_lds(
        (const __attribute__((address_space(1))) void*)(unsigned long long)g,
        (__attribute__((address_space(3))) void*)(unsigned int)(unsigned long long)l,
        16, 0, 0);
}

// raw barrier with compiler memory fences (no vmcnt(0) drain, unlike __syncthreads)
__device__ __forceinline__ void block_sync() {
    asm volatile("" ::: "memory");
    __builtin_amdgcn_s_barrier();
    asm volatile("" ::: "memory");
}
#define WAITV(n) asm volatile("s_waitcnt vmcnt(" #n ")" ::: "memory")

// pack two f32 -> one dword of 2 bf16 (RNE): lo = bf16(a), hi = bf16(b)
__device__ __forceinline__ unsigned cvtpk_bf16(float a, float b) {
    unsigned r;
    asm("v_cvt_pk_bf16_f32 %0, %1, %2" : "=v"(r) : "v"(a), "v"(b));
    return r;
}

// ---------- wave-per-row LayerNorm core: f32 in -> bf16 out, C=1024 ----------
__device__ __forceinline__ void ln_row(const float* __restrict__ xin,
                                       const float* __restrict__ w,
                                       const float* __restrict__ bb,
                                       short* __restrict__ out, int row, int lane) {
    const float4* xr = (const float4*)(xin + (long)row * 1024);
    float4 v[4];
    float s1 = 0.f, s2 = 0.f;
#pragma unroll
    for (int i = 0; i < 4; ++i) {
        v[i] = xr[lane + i * 64];
        s1 += v[i].x + v[i].y + v[i].z + v[i].w;
        s2 += v[i].x*v[i].x + v[i].y*v[i].y + v[i].z*v[i].z + v[i].w*v[i].w;
    }
#pragma unroll
    for (int off = 32; off > 0; off >>= 1) {
        s1 += __shfl_xor(s1, off, 64);
        s2 += __shfl_xor(s2, off, 64);
    }
    const float mu = s1 * (1.0f / 1024.0f);
    float var = s2 * (1.0f / 1024.0f) - mu * mu;
    var = fmaxf(var, 0.0f);
    const float rs = rsqrtf(var + 1e-5f);
    short4* orow = (short4*)(out + (long)row * 1024);
#pragma unroll
    for (int i = 0; i < 4; ++i) {
        const int ci = (lane + i * 64) * 4;
        const float4 wv = *(const float4*)(w + ci);
        const float4 bv = *(const float4*)(bb + ci);
        short4 o;
        o.x = f2bf((v[i].x - mu) * rs * wv.x + bv.x);
        o.y = f2bf((v[i].y - mu) * rs * wv.y + bv.y);
        o.z = f2bf((v[i].z - mu) * rs * wv.z + bv.z);
        o.w = f2bf((v[i].w - mu) * rs * wv.w + bv.w);
        orow[lane + i * 64] = o;
    }
}

__global__ __launch_bounds__(256) void ln_k(const float* __restrict__ xin,
                                            const float* __restrict__ w,
                                            const float* __restrict__ bb,
                                            short* __restrict__ out) {
    ln_row(xin, w, bb, out, blockIdx.x * 4 + (threadIdx.x >> 6), threadIdx.x & 63);
}

// ---------- fused: 4 weight transposes (f32 [K][N] -> bf16 [N][K]) + LN1 ----------
// 64x64 tiles, float4 reads (1 KB/wave-instr) + short4 writes (512 B/wave-instr);
// LDS [64][65] pad keeps both phases <=2-way bank aliasing (free).
__global__ __launch_bounds__(256) void pre_k(
        const float* __restrict__ w0, const float* __restrict__ w1,
        const float* __restrict__ w2, const float* __restrict__ w3,
        short* __restrict__ o0, short* __restrict__ o1,
        short* __restrict__ o2, short* __restrict__ o3,
        const float* __restrict__ x, const float* __restrict__ ln1w,
        const float* __restrict__ ln1b, short* __restrict__ xln) {
    int bid = blockIdx.x;
    if (bid >= 3072) {   // LN1: 1024 blocks, 4 rows each (wave per row)
        ln_row(x, ln1w, ln1b, xln, (bid - 3072) * 4 + (threadIdx.x >> 6), threadIdx.x & 63);
        return;
    }
    const float* in; short* out; int K, N, nx;
    if (bid < 768)       { in = w0; out = o0; K = 1024; N = 3072; nx = 48; }
    else if (bid < 1024) { bid -= 768;  in = w1; out = o1; K = 1024; N = 1024; nx = 16; }
    else if (bid < 2048) { bid -= 1024; in = w2; out = o2; K = 1024; N = 4096; nx = 64; }
    else                 { bid -= 2048; in = w3; out = o3; K = 4096; N = 1024; nx = 16; }
    const int n0 = (bid % nx) * 64, k0 = (bid / nx) * 64;
    __shared__ float tile[64][65];
    const int tx = threadIdx.x & 15, ty = threadIdx.x >> 4;  // ty 0..15
#pragma unroll
    for (int p = 0; p < 4; ++p) {
        const int k = p * 16 + ty;
        const float4 v = *(const float4*)(in + (long)(k0 + k) * N + n0 + tx * 4);
        tile[k][tx * 4 + 0] = v.x;
        tile[k][tx * 4 + 1] = v.y;
        tile[k][tx * 4 + 2] = v.z;
        tile[k][tx * 4 + 3] = v.w;
    }
    __syncthreads();
#pragma unroll
    for (int p = 0; p < 4; ++p) {
        const int n = p * 16 + ty;
        short4 o;
        o.x = f2bf(tile[tx * 4 + 0][n]);
        o.y = f2bf(tile[tx * 4 + 1][n]);
        o.z = f2bf(tile[tx * 4 + 2][n]);
        o.w = f2bf(tile[tx * 4 + 3][n]);
        *(short4*)(out + (long)(n0 + n) * K + k0 + tx * 4) = o;
    }
}

// ---------- GEMM epilogue ----------
// EPI 1 GELU: tanh-form (sigmoid identity), |delta vs exact erf| < 3e-3 << bf16 tol.
template <int EPI, typename OutT>
__device__ __forceinline__ void epi_store(OutT* out, const float* resid, long oidx, float v) {
    if constexpr (EPI == 0) {
        out[oidx] = f2bf(v);
    } else if constexpr (EPI == 1) {
        const float u = v * (0.79788456080f + 0.03567740814f * v * v);
        v = v / (1.0f + __expf(-2.0f * u));
        out[oidx] = f2bf(v);
    } else {
        v += resid[oidx];
        out[oidx] = v;   // f32 store
    }
}

// ---------- GEMM 128x128, BK=32, TRIPLE-buffered, counted vmcnt, 1 barrier/step ----------
// LDS = 48 KB (3 blocks/CU). Tile s+2 stages into buf (s+2)%3 == (s-1)%3, whose
// ds_reads all completed before any wave passed THIS barrier -> no WAR hazard,
// no second barrier. WAITV(4): tile s resident, tile s+1's loads in flight.
template <int EPI, typename OutT>
__global__ __launch_bounds__(256) void gemm_k(const short* __restrict__ A,
                                              const short* __restrict__ Bt,
                                              const float* __restrict__ bias,
                                              const float* __restrict__ resid,
                                              OutT* __restrict__ out,
                                              int M, int N, int K) {
    __shared__ __align__(16) short sA[3][128 * 32];
    __shared__ __align__(16) short sB[3][128 * 32];
    const int tid = threadIdx.x;
    const int lane = tid & 63, wave = tid >> 6;
    const int wr = (wave >> 1) * 64, wc = (wave & 1) * 64;
    const int lrow = lane & 15, quad = lane >> 4;
    const int bm = blockIdx.y * 128, bn = blockIdx.x * 128;
    const short* Ap = A + (long)(bm + (tid >> 2)) * K + (tid & 3) * 8;
    const short* Bp = Bt + (long)(bn + (tid >> 2)) * K + (tid & 3) * 8;
    const long rowstep = (long)64 * K;

    auto stage = [&](int q, int k0) {
        gl2lds16(Ap + k0,           sA[q] + tid * 8);
        gl2lds16(Ap + rowstep + k0, sA[q] + 2048 + tid * 8);
        gl2lds16(Bp + k0,           sB[q] + tid * 8);
        gl2lds16(Bp + rowstep + k0, sB[q] + 2048 + tid * 8);
    };

    f32x4 acc[4][4] = {};
    const int S = K >> 5;
    stage(0, 0);
    stage(1, 32);
    int cur = 0, nx2 = 2;
    for (int s = 0; s < S; ++s) {
        if (s + 1 < S) { WAITV(4); } else { WAITV(0); }   // tile s resident
        block_sync();
        if (s + 2 < S) stage(nx2, (s + 2) << 5);          // writes buf (s-1)%3: safe
        const short* pA = sA[cur];
        const short* pB = sB[cur];
        s8x af[4], bfr[4];
#pragma unroll
        for (int i = 0; i < 4; ++i) af[i]  = *(const s8x*)(pA + (wr + i*16 + lrow) * 32 + quad * 8);
#pragma unroll
        for (int j = 0; j < 4; ++j) bfr[j] = *(const s8x*)(pB + (wc + j*16 + lrow) * 32 + quad * 8);
#pragma unroll
        for (int i = 0; i < 4; ++i)
#pragma unroll
            for (int j = 0; j < 4; ++j)
                acc[i][j] = __builtin_amdgcn_mfma_f32_16x16x32_bf16(af[i], bfr[j], acc[i][j], 0, 0, 0);
        cur = (cur == 2) ? 0 : cur + 1;
        nx2 = (nx2 == 2) ? 0 : nx2 + 1;
    }
#pragma unroll
    for (int i = 0; i < 4; ++i) {
#pragma unroll
        for (int j = 0; j < 4; ++j) {
#pragma unroll
            for (int r = 0; r < 4; ++r) {
                const int row = bm + wr + i*16 + quad*4 + r;   // C/D: row = quad*4 + reg
                const int col = bn + wc + j*16 + lrow;         // C/D: col = lane&15
                epi_store<EPI>(out, resid, (long)row * N + col, acc[i][j][r] + bias[col]);
            }
        }
    }
}

// ---------- GEMM 256x128, BK=32, TRIPLE-buffered, counted vmcnt, 1 barrier/step ----------
// Tile-growth variant of the proven gemm_k skeleton (identical sync structure /
// WAR argument): 4 waves each own 64 rows x 128 cols -> 32 MFMA per wave per
// barrier (2x gemm_k), 24 KB staged per 2.1 MFLOP (-25% bytes/FLOP), B-panel
// HBM re-reads halved (M/BM 16 vs 32). LDS 72 KB -> 2 blocks/CU; acc 4x8 f32x4
// = 128 VGPR, fits 2 waves/SIMD (launch_bounds(256,2)).
template <int EPI, typename OutT>
__global__ __launch_bounds__(256, 2) void gemm256_k(const short* __restrict__ A,
                                                    const short* __restrict__ Bt,
                                                    const float* __restrict__ bias,
                                                    const float* __restrict__ resid,
                                                    OutT* __restrict__ out,
                                                    int M, int N, int K) {
    __shared__ __align__(16) short sA[3][256 * 32];
    __shared__ __align__(16) short sB[3][128 * 32];
    const int tid = threadIdx.x;
    const int lane = tid & 63, wave = tid >> 6;
    const int wr = wave * 64;
    const int lrow = lane & 15, quad = lane >> 4;
    const int bm = blockIdx.y * 256, bn = blockIdx.x * 128;
    const short* Ap = A + (long)(bm + (tid >> 2)) * K + (tid & 3) * 8;
    const short* Bp = Bt + (long)(bn + (tid >> 2)) * K + (tid & 3) * 8;
    const long rowstep = (long)64 * K;

    auto stage = [&](int q, int k0) {
        gl2lds16(Ap + k0,               sA[q] + tid * 8);
        gl2lds16(Ap + rowstep + k0,     sA[q] + 2048 + tid * 8);
        gl2lds16(Ap + 2 * rowstep + k0, sA[q] + 4096 + tid * 8);
        gl2lds16(Ap + 3 * rowstep + k0, sA[q] + 6144 + tid * 8);
        gl2lds16(Bp + k0,               sB[q] + tid * 8);
        gl2lds16(Bp + rowstep + k0,     sB[q] + 2048 + tid * 8);
    };

    f32x4 acc[4][8] = {};
    const int S = K >> 5;
    stage(0, 0);
    stage(1, 32);
    int cur = 0, nx2 = 2;
    for (int s = 0; s < S; ++s) {
        if (s + 1 < S) { WAITV(6); } else { WAITV(0); }   // tile s resident
        block_sync();
        if (s + 2 < S) stage(nx2, (s + 2) << 5);          // buf (s-1)%3: WAR-safe
        const short* pA = sA[cur];
        const short* pB = sB[cur];
        s8x af[4], bfr[8];
#pragma unroll
        for (int i = 0; i < 4; ++i) af[i]  = *(const s8x*)(pA + (wr + i*16 + lrow) * 32 + quad * 8);
#pragma unroll
        for (int j = 0; j < 8; ++j) bfr[j] = *(const s8x*)(pB + (j*16 + lrow) * 32 + quad * 8);
#pragma unroll
        for (int i = 0; i < 4; ++i)
#pragma unroll
            for (int j = 0; j < 8; ++j)
                acc[i][j] = __builtin_amdgcn_mfma_f32_16x16x32_bf16(af[i], bfr[j], acc[i][j], 0, 0, 0);
        cur = (cur == 2) ? 0 : cur + 1;
        nx2 = (nx2 == 2) ? 0 : nx2 + 1;
    }
#pragma unroll
    for (int i = 0; i < 4; ++i) {
#pragma unroll
        for (int j = 0; j < 8; ++j) {
#pragma unroll
            for (int r = 0; r < 4; ++r) {
                const int row = bm + wr + i*16 + quad*4 + r;
                const int col = bn + j*16 + lrow;
                epi_store<EPI>(out, resid, (long)row * N + col, acc[i][j][r] + bias[col]);
            }
        }
    }
}

// ---------- GEMM 128x64, BK=64 (2x32 panels), double-buffered, XCD-swizzled ----------
// Round-9-verified best config for the skinny-N GEMMs (proj, mlp): 54.7 us mlp.
template <int EPI, typename OutT>
__global__ __launch_bounds__(256) void gemm128x64_k(const short* __restrict__ A,
                                                    const short* __restrict__ Bt,
                                                    const float* __restrict__ bias,
                                                    const float* __restrict__ resid,
                                                    OutT* __restrict__ out,
                                                    int M, int N, int K) {
    __shared__ __align__(16) short sA[2][2][128 * 32];
    __shared__ __align__(16) short sB[2][2][64 * 32];
    const int tid = threadIdx.x;
    const int lane = tid & 63, wave = tid >> 6;
    const int wr = (wave >> 1) * 64, wc = (wave & 1) * 32;
    const int lrow = lane & 15, quad = lane >> 4;
    // XCD-chunked bijective swizzle (nwg = 512, %8 == 0)
    const int gx = gridDim.x;
    const int nwg = gx * gridDim.y;
    const int bid = blockIdx.y * gx + blockIdx.x;
    const int swz = (bid & 7) * (nwg >> 3) + (bid >> 3);
    const int bm = (swz / gx) * 128, bn = (swz % gx) * 64;
    const short* Ap = A + (long)(bm + (tid >> 2)) * K + (tid & 3) * 8;
    const short* Bp = Bt + (long)(bn + (tid >> 2)) * K + (tid & 3) * 8;
    const long rowstep = (long)64 * K;

    auto stage = [&](int p, int k0) {
#pragma unroll
        for (int hp = 0; hp < 2; ++hp) {
            gl2lds16(Ap + k0 + hp * 32,           sA[p][hp] + tid * 8);
            gl2lds16(Ap + rowstep + k0 + hp * 32, sA[p][hp] + 2048 + tid * 8);
            gl2lds16(Bp + k0 + hp * 32,           sB[p][hp] + tid * 8);
        }
    };

    f32x4 acc[4][2] = {};
    stage(0, 0);
    const int S = K >> 6;
    for (int s = 0; s < S; ++s) {
        const int p = s & 1;
        __syncthreads();
        if (s + 1 < S) stage(p ^ 1, (s + 1) << 6);
#pragma unroll
        for (int hp = 0; hp < 2; ++hp) {
            s8x af[4], bfr[2];
#pragma unroll
            for (int i = 0; i < 4; ++i) af[i]  = *(const s8x*)(sA[p][hp] + (wr + i*16 + lrow) * 32 + quad * 8);
#pragma unroll
            for (int j = 0; j < 2; ++j) bfr[j] = *(const s8x*)(sB[p][hp] + (wc + j*16 + lrow) * 32 + quad * 8);
#pragma unroll
            for (int i = 0; i < 4; ++i)
#pragma unroll
                for (int j = 0; j < 2; ++j)
                    acc[i][j] = __builtin_amdgcn_mfma_f32_16x16x32_bf16(af[i], bfr[j], acc[i][j], 0, 0, 0);
        }
    }
#pragma unroll
    for (int i = 0; i < 4; ++i) {
#pragma unroll
        for (int j = 0; j < 2; ++j) {
#pragma unroll
            for (int r = 0; r < 4; ++r) {
                const int row = bm + wr + i*16 + quad*4 + r;
                const int col = bn + wc + j*16 + lrow;
                epi_store<EPI>(out, resid, (long)row * N + col, acc[i][j][r] + bias[col]);
            }
        }
    }
}

// ---------- attention common constants ----------
#define ATT_CS (0.125f * 1.4426950408889634f)  /* log2(e)/sqrt(64) */
#define ATT_C0 (14.426950408889634f)           /* 10*log2(e) fixed shift */

// hw transpose read: lane l receives column (l&15), rows j=0..3 of the [4][16]
// bf16 tile in the 128B window (l>>4); vaddr = base + lane*8B, offset literal.
#define TR16(dst, off) \
    asm volatile("ds_read_b64_tr_b16 %0, %1 offset:" off : "=v"(dst) : "v"(tva))

// ---------- paired-tile causal flash attention: B=2,H=16,T=2048,hs=64 ----------
// Pairs (bx, 31-bx): every block exactly 33 tile-iterations. Swapped QK^T
// (mfma(K,Q)) -> in-register softmax; P pack via v_cvt_pk_bf16_f32; row-sum l
// via ones-MFMA on pa fragments (l lands in C/D row layout, no shuffles).
__global__ __launch_bounds__(256) void attn_k(const short* __restrict__ qkv,
                                              short* __restrict__ y) {
    const int bx = blockIdx.x;                 // 0..15
    const int b = blockIdx.y >> 4, h = blockIdx.y & 15;
    const int qtA = bx, qtB = 31 - bx;
    const int tid = threadIdx.x, lane = tid & 63, wave = tid >> 6;
    const int lrow = lane & 15, quad = lane >> 4;
    const long base = (long)b * 2048 * 3072;

    __shared__ __align__(16) short sK[3][64 * 64];
    __shared__ __align__(16) short sV[3][4096];

    s8x qfA0, qfA1, qfB0, qfB1;
    {
        const short* qpA = qkv + base + (long)(qtA * 64 + wave * 16 + lrow) * 3072 + h * 64 + quad * 8;
        qfA0 = *(const s8x*)qpA; qfA1 = *(const s8x*)(qpA + 32);
        const short* qpB = qkv + base + (long)(qtB * 64 + wave * 16 + lrow) * 3072 + h * 64 + quad * 8;
        qfB0 = *(const s8x*)qpB; qfB1 = *(const s8x*)(qpB + 32);
    }
    f32x4 oA[4], oB[4], lA4 = {}, lB4 = {};
#pragma unroll
    for (int d = 0; d < 4; ++d) { oA[d] = f32x4{0.f,0.f,0.f,0.f}; oB[d] = f32x4{0.f,0.f,0.f,0.f}; }
    s8x ones;
#pragma unroll
    for (int j = 0; j < 8; ++j) ones[j] = (short)0x3F80;   // bf16 1.0

    // K staging (XOR-swizzled rows)
    const int srow = tid >> 3, sg = tid & 7;
    const int sw0 = ((srow & 7) ^ (srow >> 3)) & 7;
    const int sw1 = (((srow + 32) & 7) ^ ((srow + 32) >> 3)) & 7;
    const short* kbase = qkv + base + 1024 + h * 64;
    auto issueK = [&](int q, int k0) {
        gl2lds16(kbase + (long)(k0 + srow) * 3072      + (sg ^ sw0) * 8, sK[q] + tid * 8);
        gl2lds16(kbase + (long)(k0 + srow + 32) * 3072 + (sg ^ sw1) * 8, sK[q] + 2048 + tid * 8);
    };

    // V staging: pre-swizzled global source -> linear LDS (subtiled-for-tr layout)
    const int vslot   = (tid >> 3) & 7;
    const int vkbl    = 2 * (vslot & 3) + (vslot >> 2);
    const int vklocal = vkbl * 4 + ((tid >> 1) & 3);
    const short* vsrc = qkv + base + 2048 + h * 64
                      + (long)vklocal * 3072 + wave * 16 + 8 * (tid & 1);
    auto issueV = [&](int q, int k0) {
        gl2lds16(vsrc + (long)k0 * 3072,        sV[q] + tid * 8);        // ks=0 half
        gl2lds16(vsrc + (long)(k0 + 32) * 3072, sV[q] + 2048 + tid * 8); // ks=1 half
    };
    const unsigned trb = (unsigned)(unsigned long long)(&sV[0][0]) + (unsigned)lane * 8u;

    // swapped QK^T: st col = q (lane&15), row = key-local (quad*4+r)
    auto tile_step = [&](const s8x& qf0, const s8x& qf1, const s8x* kf0, const s8x* kf1,
                         const s8x (*vfr)[4], f32x4* o, f32x4& lacc, int qt, int kt, int k0) {
        f32x4 s[4];
#pragma unroll
        for (int ct = 0; ct < 4; ++ct) {
            f32x4 t = f32x4{0.f, 0.f, 0.f, 0.f};
            t = __builtin_amdgcn_mfma_f32_16x16x32_bf16(kf0[ct], qf0, t, 0, 0, 0);
            t = __builtin_amdgcn_mfma_f32_16x16x32_bf16(kf1[ct], qf1, t, 0, 0, 0);
            s[ct] = t;
        }
        const int qrow = qt * 64 + wave * 16 + lrow;   // this lane's q
        float pm[4][4];
        if (kt == qt) {           // diagonal tile masking (uniform branch)
#pragma unroll
            for (int ct = 0; ct < 4; ++ct)
#pragma unroll
                for (int r = 0; r < 4; ++r) {
                    const int key = k0 + ct * 16 + quad * 4 + r;
                    const float pp = exp2f(fmaf(s[ct][r], ATT_CS, -ATT_C0));
                    pm[ct][r] = (key > qrow) ? 0.f : pp;
                }
        } else {
#pragma unroll
            for (int ct = 0; ct < 4; ++ct)
#pragma unroll
                for (int r = 0; r < 4; ++r)
                    pm[ct][r] = exp2f(fmaf(s[ct][r], ATT_CS, -ATT_C0));
        }

        // pack P -> bf16 pairs (RNE): w2[ct][p] = keys {ct*16+4*quad+2p, +1}, q=lrow
        unsigned int w2[4][2];
#pragma unroll
        for (int ct = 0; ct < 4; ++ct)
#pragma unroll
            for (int p2 = 0; p2 < 2; ++p2)
                w2[ct][p2] = cvtpk_bf16(pm[ct][2 * p2], pm[ct][2 * p2 + 1]);
        // PV A-frag (lane needs P[q=lane&15][k=quad*8+e], e=0..7) via lane swaps
        s8x pa[2];
#pragma unroll
        for (int ks = 0; ks < 2; ++ks) {
            auto rAC = __builtin_amdgcn_permlane32_swap((int)w2[2 * ks][0], (int)w2[2 * ks + 1][0], false, false);
            auto rBD = __builtin_amdgcn_permlane32_swap((int)w2[2 * ks][1], (int)w2[2 * ks + 1][1], false, false);
            auto mAC = __builtin_amdgcn_permlane16_swap(rAC[0], rAC[1], false, false);
            auto mBD = __builtin_amdgcn_permlane16_swap(rBD[0], rBD[1], false, false);
            int4 f;
            f.x = mAC[0]; f.y = mBD[0]; f.z = mAC[1]; f.w = mBD[1];
            pa[ks] = *(const s8x*)&f;
        }
#pragma unroll
        for (int ks = 0; ks < 2; ++ks) {
            lacc = __builtin_amdgcn_mfma_f32_16x16x32_bf16(pa[ks], ones, lacc, 0, 0, 0);
#pragma unroll
            for (int dt = 0; dt < 4; ++dt)
                o[dt] = __builtin_amdgcn_mfma_f32_16x16x32_bf16(pa[ks], vfr[ks][dt], o[dt], 0, 0, 0);
        }
    };

    issueK(0, 0);   issueV(0, 0);
    issueK(1, 64);  issueV(1, 64);   // qtB >= 16: tile 1 always exists
    int cur = 0, nx2 = 2;
    for (int kt = 0; kt <= qtB; ++kt) {
        const int k0 = kt * 64;
        if (kt < qtB) { WAITV(4); } else { WAITV(0); }   // tile kt resident
        block_sync();
        if (kt + 2 <= qtB) { issueK(nx2, k0 + 128); issueV(nx2, k0 + 128); }

        // K fragments (compiler-managed LDS reads)
        s8x kf0[4], kf1[4];
#pragma unroll
        for (int ct = 0; ct < 4; ++ct) {
            const int row = ct * 16 + lrow;
            const int swr = ((row & 7) ^ (row >> 3)) & 7;
            kf0[ct] = *(const s8x*)(sK[cur] + row * 64 + ((quad ^ swr) * 8));
            kf1[ct] = *(const s8x*)(sK[cur] + row * 64 + (((4 + quad) ^ swr) * 8));
        }

        // V fragments via hw transpose reads (shared by both q-tiles)
        const unsigned tva = trb + (unsigned)(cur << 13);
        i32x2 tr[16];
        TR16(tr[0],  "0");    TR16(tr[1],  "512");
        TR16(tr[2],  "1024"); TR16(tr[3],  "1536");
        TR16(tr[4],  "2048"); TR16(tr[5],  "2560");
        TR16(tr[6],  "3072"); TR16(tr[7],  "3584");
        TR16(tr[8],  "4096"); TR16(tr[9],  "4608");
        TR16(tr[10], "5120"); TR16(tr[11], "5632");
        TR16(tr[12], "6144"); TR16(tr[13], "6656");
        TR16(tr[14], "7168"); TR16(tr[15], "7680");
        asm volatile("s_waitcnt lgkmcnt(0)" ::: "memory");
        __builtin_amdgcn_sched_barrier(0);       // rule #18: pin MFMAs after the wait
        s8x vfr[2][4];
#pragma unroll
        for (int ks = 0; ks < 2; ++ks)
#pragma unroll
            for (int dt = 0; dt < 4; ++dt) {
                const int i2 = ks * 8 + dt * 2;
                int4 f;
                f.x = tr[i2][0]; f.y = tr[i2][1];
                f.z = tr[i2 + 1][0]; f.w = tr[i2 + 1][1];
                vfr[ks][dt] = *(const s8x*)&f;
            }

        if (kt <= qtA) tile_step(qfA0, qfA1, kf0, kf1, vfr, oA, lA4, qtA, kt, k0);
        tile_step(qfB0, qfB1, kf0, kf1, vfr, oB, lB4, qtB, kt, k0);

        cur = (cur == 2) ? 0 : cur + 1;
        nx2 = (nx2 == 2) ? 0 : nx2 + 1;
    }

    // l via ones-MFMA already lives at row = quad*4 + r (matches O rows): no shuffles
    float rA[4], rB[4];
#pragma unroll
    for (int r = 0; r < 4; ++r) {
        rA[r] = 1.0f / lA4[r];
        rB[r] = 1.0f / lB4[r];
    }
#pragma unroll
    for (int dt = 0; dt < 4; ++dt) {
#pragma unroll
        for (int r = 0; r < 4; ++r) {
            const int qA = qtA * 64 + wave * 16 + quad * 4 + r;
            const int qB = qtB * 64 + wave * 16 + quad * 4 + r;
            y[((long)b * 2048 + qA) * 1024 + h * 64 + dt * 16 + lrow] = f2bf(oA[dt][r] * rA[r]);
            y[((long)b * 2048 + qB) * 1024 + h * 64 + dt * 16 + lrow] = f2bf(oB[dt][r] * rB[r]);
        }
    }
}

// ---------- launch ----------
extern "C" void kernel_launch(void* const* d_in, const int* in_sizes, int n_in,
                              void* d_out, int out_size, void* d_ws, size_t ws_size,
                              hipStream_t stream) {
    const float* x      = (const float*)d_in[0];
    const float* ln1_w  = (const float*)d_in[1];
    const float* ln1_b  = (const float*)d_in[2];
    const float* attn_w = (const float*)d_in[3];
    const float* attn_b = (const float*)d_in[4];
    const float* proj_w = (const float*)d_in[5];
    const float* proj_b = (const float*)d_in[6];
    const float* ln2_w  = (const float*)d_in[7];
    const float* ln2_b  = (const float*)d_in[8];
    const float* fc_w   = (const float*)d_in[9];
    const float* fc_b   = (const float*)d_in[10];
    const float* mlp_w  = (const float*)d_in[11];
    const float* mlp_b  = (const float*)d_in[12];

    char* ws = (char*)d_ws;
    short* attn_wt = (short*)(ws + 0);           // [3072,1024] bf16
    short* proj_wt = (short*)(ws + 6291456L);    // [1024,1024] bf16
    short* fc_wt   = (short*)(ws + 8388608L);    // [4096,1024] bf16
    short* mlp_wt  = (short*)(ws + 16777216L);   // [1024,4096] bf16
    short* slotA   = (short*)(ws + 25165824L);   // xln / y / h  [4096,1024] bf16
    short* slotB   = (short*)(ws + 33554432L);   // qkv [4096,3072] / hh [4096,4096] bf16
    // total ws use: 67,108,864 bytes (64 MB)

    short* xln  = slotA;
    short* yb   = slotA;
    short* hb   = slotA;
    short* qkvb = slotB;
    short* hh   = slotB;
    float* x1   = (float*)d_out;   // f32 residual stream lives in d_out
    float* outp = (float*)d_out;

    // transposes + LN1 fused (independent inputs)
    pre_k<<<4096, 256, 0, stream>>>(attn_w, proj_w, fc_w, mlp_w,
                                    attn_wt, proj_wt, fc_wt, mlp_wt,
                                    x, ln1_w, ln1_b, xln);

    gemm_k<0, short><<<dim3(24, 32), 256, 0, stream>>>(xln, attn_wt, attn_b, nullptr, qkvb, 4096, 3072, 1024);
    attn_k<<<dim3(16, 32), 256, 0, stream>>>(qkvb, yb);
    gemm128x64_k<2, float><<<dim3(16, 32), 256, 0, stream>>>(yb, proj_wt, proj_b, x, x1, 4096, 1024, 1024);
    ln_k<<<1024, 256, 0, stream>>>(x1, ln2_w, ln2_b, hb);
    gemm256_k<1, short><<<dim3(32, 16), 256, 0, stream>>>(hb, fc_wt, fc_b, nullptr, hh, 4096, 4096, 1024);
    gemm128x64_k<3, float><<<dim3(16, 32), 256, 0, stream>>>(hh, mlp_wt, mlp_b, x1, outp, 4096, 1024, 4096);
}